// Round 18
// baseline (735.012 us; speedup 1.0000x reference)
//
#include <hip/hip_runtime.h>
#include <hip/hip_bf16.h>

// ---------------- problem constants ----------------
constexpr int B_   = 8;
constexpr int D_   = 512;
constexpr int L0_  = 1024;
constexpr int L_   = 1025;          // L0 + cls
constexpr int H_   = 8;
constexpr int DH_  = 64;
constexpr int DFF_ = 2048;
constexpr int NLAYER_ = 2;
constexpr int M_   = B_ * L_;       // 8200 rows
constexpr int LP_  = 1088;          // padded L for Vt (17*64)
constexpr int NQT_ = 9;             // ceil(L/128) attn q-tiles
constexpr int NSPLIT_ = 2;          // K-range partitions (flash-decoding)
constexpr float EPS_   = 1e-6f;
constexpr float SCALE_ = 0.125f;    // 1/sqrt(64)

#define DEV_INLINE __device__ __forceinline__

typedef __attribute__((ext_vector_type(8))) __bf16 bf16x8;
typedef __attribute__((ext_vector_type(4))) __bf16 bf16x4;
typedef __attribute__((ext_vector_type(4))) float  f32x4;
typedef __attribute__((ext_vector_type(4))) unsigned int u32x4;

union U4 { uint32_t u[4]; bf16x8 f; };

DEV_INLINE float gelu_exact(float x) {
    return 0.5f * x * (1.f + erff(x * 0.70710678118654752f));
}

struct bfpair { __bf16 h, l; };
DEV_INLINE bfpair split_bf(float v) {
    bfpair p;
    p.h = (__bf16)v;
    p.l = (__bf16)(v - (float)p.h);
    return p;
}
DEV_INLINE uint16_t bfbits(float v) {
    __bf16 h = (__bf16)v;
    return __builtin_bit_cast(uint16_t, h);
}
DEV_INLINE uint32_t pk2f(float a, float b) {
    return (uint32_t)bfbits(a) | ((uint32_t)bfbits(b) << 16);
}
DEV_INLINE uint32_t pkhl(float v) {
    bfpair s = split_bf(v);
    return (uint32_t)__builtin_bit_cast(uint16_t, s.h)
         | ((uint32_t)__builtin_bit_cast(uint16_t, s.l) << 16);
}
DEV_INLINE void unpk8(const uint32_t* r, bf16x8& h, bf16x8& l) {
    U4 uh, ul;
#pragma unroll
    for (int i = 0; i < 4; ++i) {
        uint32_t a = r[2 * i], b = r[2 * i + 1];
        uh.u[i] = (a & 0xffffu) | (b << 16);
        ul.u[i] = (a >> 16) | (b & 0xffff0000u);
    }
    h = uh.f; l = ul.f;
}
// hi plane only (attention QK^T path)
DEV_INLINE bf16x8 unpk8h(const uint32_t* r) {
    U4 uh;
#pragma unroll
    for (int i = 0; i < 4; ++i) {
        uint32_t a = r[2 * i], b = r[2 * i + 1];
        uh.u[i] = (a & 0xffffu) | (b << 16);
    }
    return uh.f;
}

// ---- async global->LDS, 16B per lane (dest = wave-uniform base + lane*16) ----
DEV_INLINE void gload16(const __bf16* g, __bf16* l) {
    __builtin_amdgcn_global_load_lds(
        (const __attribute__((address_space(1))) void*)g,
        (__attribute__((address_space(3))) void*)l,
        16, 0, 0);
}

// ---------------- fp32 -> bf16 hi/lo plane split (weights) ----------------
__global__ __launch_bounds__(256) void split_w_kernel(
    const float* __restrict__ src, __bf16* __restrict__ hi,
    __bf16* __restrict__ lo, int n4) {
    int i = blockIdx.x * 256 + threadIdx.x;
    if (i >= n4) return;
    float4 v = *(const float4*)&src[i * 4];
    bf16x4 h, l;
    bfpair p0 = split_bf(v.x); h[0] = p0.h; l[0] = p0.l;
    bfpair p1 = split_bf(v.y); h[1] = p1.h; l[1] = p1.l;
    bfpair p2 = split_bf(v.z); h[2] = p2.h; l[2] = p2.l;
    bfpair p3 = split_bf(v.w); h[3] = p3.h; l[3] = p3.l;
    *(bf16x4*)&hi[i * 4] = h;
    *(bf16x4*)&lo[i * 4] = l;
}

// ---------------- fp32 -> bf16 (hi only) ----------------
__global__ __launch_bounds__(256) void tobf16_kernel(
    const float* __restrict__ src, __bf16* __restrict__ dst, int n4) {
    int i = blockIdx.x * 256 + threadIdx.x;
    if (i >= n4) return;
    float4 v = *(const float4*)&src[i * 4];
    bf16x4 h;
    h[0] = (__bf16)v.x; h[1] = (__bf16)v.y;
    h[2] = (__bf16)v.z; h[3] = (__bf16)v.w;
    *(bf16x4*)&dst[i * 4] = h;
}

// ---------------- zero Vt pad tokens (l = L_..LP_-1) ----------------
// CRITICAL: pad tokens feed PV MFMA with P=0; garbage bits there can alias
// bf16 Inf/NaN and 0*Inf = NaN (R10 failure). Must be zeroed every layer.
__global__ __launch_bounds__(256) void zero_vt_pad_kernel(uint32_t* __restrict__ Vt) {
    constexpr int PAD = LP_ - L_;                 // 63
    int idx = blockIdx.x * 256 + threadIdx.x;
    int total = B_ * H_ * DH_ * PAD;
    if (idx >= total) return;
    int row = idx / PAD;
    int c   = idx - row * PAD;
    Vt[(size_t)row * LP_ + L_ + c] = 0u;
}

// ---------------- build x1/x2 ----------------
__global__ __launch_bounds__(256) void write_cls_kernel(
    const float* __restrict__ cls, float* __restrict__ X1, float* __restrict__ X2) {
    int idx = blockIdx.x * 256 + threadIdx.x;
    int b = idx >> 9;
    int d = idx & 511;
    float v = cls[d];
    X1[(size_t)b * L_ * D_ + d] = v;
    X2[(size_t)b * L_ * D_ + d] = v;
}

// embed [B, D, L0] -> X rows 1..L0
__global__ __launch_bounds__(256) void transpose_embed_kernel(
    const float* __restrict__ e, float* __restrict__ X) {
    __shared__ float tile[32][33];
    int b  = blockIdx.z;
    int i0 = blockIdx.x * 32;
    int d0 = blockIdx.y * 32;
    int tx = threadIdx.x;
    int ty = threadIdx.y;
#pragma unroll
    for (int j = 0; j < 32; j += 8)
        tile[ty + j][tx] = e[((size_t)b * D_ + d0 + ty + j) * L0_ + i0 + tx];
    __syncthreads();
#pragma unroll
    for (int j = 0; j < 32; j += 8)
        X[((size_t)b * L_ + 1 + i0 + ty + j) * D_ + d0 + tx] = tile[tx][ty + j];
}

// ---------------- 2-pass MFMA GEMM, double-buffered gload_lds staging ----------------
// C = A*W^T + bias; A bf16-hi in global, W hi/lo planes -> C = A*(W_h+W_l).
// Per k-step: sync (drain own DMA + barrier), issue next-tile DMA into buf^1,
// compute current buf. DMA latency hides under MFMA; ONE barrier per step.
// OUTMODE: 0 = fp32 C, 1 = packed u32 (hi|lo) Cpk, 2 = bf16-hi Ch.
template <bool GELU, int OUTMODE>
__global__ __launch_bounds__(256) void gemm_mfma_kernel(
    const __bf16* __restrict__ A,
    const __bf16* __restrict__ Wh, const __bf16* __restrict__ Wl,
    const float* __restrict__ bias, float* __restrict__ C,
    uint32_t* __restrict__ Cpk, __bf16* __restrict__ Ch,
    int M, int N, int K) {
    constexpr int BM = 128, BN = 64, BK = 32;
    constexpr int ASZ = BM * BK;       // 4096 bf16
    constexpr int WSZ = BN * BK;       // 2048 bf16
    __shared__ alignas(16) __bf16 Ahs[2][ASZ];
    __shared__ alignas(16) __bf16 Bhs[2][WSZ];
    __shared__ alignas(16) __bf16 Bls[2][WSZ];

    const int GM = (M + BM - 1) / BM;
    const int nwg = gridDim.x;
    int bid = blockIdx.x;
    {
        int q = nwg >> 3, r = nwg & 7;
        int xcd = bid & 7, pos = bid >> 3;
        bid = (xcd < r) ? xcd * (q + 1) + pos
                        : r * (q + 1) + (xcd - r) * q + pos;
    }
    const int bn = bid / GM;
    const int bm = bid % GM;
    const int m0 = bm * BM;
    const int n0 = bn * BN;

    const int tid  = threadIdx.x;
    const int lane = tid & 63;
    const int wv   = tid >> 6;
    const int wr   = wv >> 1;
    const int wc   = wv & 1;
    const int fr   = lane & 15;
    const int fq   = lane >> 4;
    const int fq8  = fq * 8;
    const int mb   = wr * 64;
    const int nb   = wc * 32;

    // gload geometry: lane -> (row = lane/4, col = (lane&3)*8 bf16)
    const int acol = (lane & 3) * 8;
    int ar0 = m0 + wv * 32 + (lane >> 2);
    int ar1 = ar0 + 16;
    if (ar0 > M - 1) ar0 = M - 1;
    if (ar1 > M - 1) ar1 = M - 1;
    const __bf16* aG0 = A + (size_t)ar0 * K + acol;
    const __bf16* aG1 = A + (size_t)ar1 * K + acol;
    const int aLoff0 = wv * 1024 + lane * 8;
    const int aLoff1 = aLoff0 + 512;
    const int wrow = n0 + wv * 16 + (lane >> 2);
    const __bf16* wGh = Wh + (size_t)wrow * K + acol;
    const __bf16* wGl = Wl + (size_t)wrow * K + acol;
    const int wLoff = wv * 512 + lane * 8;

    f32x4 acc[4][2];
#pragma unroll
    for (int i = 0; i < 4; ++i)
#pragma unroll
        for (int j = 0; j < 2; ++j) acc[i][j] = (f32x4){0.f, 0.f, 0.f, 0.f};

    const int nk = K / BK;
    // prologue: DMA tile 0 -> buf 0
    gload16(aG0, &Ahs[0][aLoff0]);
    gload16(aG1, &Ahs[0][aLoff1]);
    gload16(wGh, &Bhs[0][wLoff]);
    gload16(wGl, &Bls[0][wLoff]);

    int buf = 0;
    for (int kt = 0; kt < nk; ++kt) {
        __syncthreads();              // drain own DMA (vmcnt) + all reads of buf^1 done

        if (kt + 1 < nk) {
            const int k1 = (kt + 1) * BK;
            const int nb2 = buf ^ 1;
            gload16(aG0 + k1, &Ahs[nb2][aLoff0]);
            gload16(aG1 + k1, &Ahs[nb2][aLoff1]);
            gload16(wGh + k1, &Bhs[nb2][wLoff]);
            gload16(wGl + k1, &Bls[nb2][wLoff]);
        }

        bf16x8 ah[4], bh[2], bl[2];
#pragma unroll
        for (int i = 0; i < 4; ++i)
            ah[i] = *(bf16x8*)&Ahs[buf][(mb + i * 16 + fr) * BK + fq8];
#pragma unroll
        for (int j = 0; j < 2; ++j) {
            bh[j] = *(bf16x8*)&Bhs[buf][(nb + j * 16 + fr) * BK + fq8];
            bl[j] = *(bf16x8*)&Bls[buf][(nb + j * 16 + fr) * BK + fq8];
        }
#pragma unroll
        for (int i = 0; i < 4; ++i)
#pragma unroll
            for (int j = 0; j < 2; ++j)
                acc[i][j] = __builtin_amdgcn_mfma_f32_16x16x32_bf16(ah[i], bh[j], acc[i][j], 0, 0, 0);
#pragma unroll
        for (int i = 0; i < 4; ++i)
#pragma unroll
            for (int j = 0; j < 2; ++j)
                acc[i][j] = __builtin_amdgcn_mfma_f32_16x16x32_bf16(ah[i], bl[j], acc[i][j], 0, 0, 0);
        buf ^= 1;
    }

    const int ccol0 = n0 + nb + fr;
    const float b0 = bias[ccol0];
    const float b1 = bias[ccol0 + 16];
#pragma unroll
    for (int i = 0; i < 4; ++i) {
#pragma unroll
        for (int r = 0; r < 4; ++r) {
            int row = m0 + mb + i * 16 + fq * 4 + r;
            if (row < M) {
                float v0 = acc[i][0][r] + b0;
                float v1 = acc[i][1][r] + b1;
                if (GELU) { v0 = gelu_exact(v0); v1 = gelu_exact(v1); }
                if (OUTMODE == 1) {
                    Cpk[(size_t)row * N + ccol0]      = pkhl(v0);
                    Cpk[(size_t)row * N + ccol0 + 16] = pkhl(v1);
                } else if (OUTMODE == 2) {
                    Ch[(size_t)row * N + ccol0]      = (__bf16)v0;
                    Ch[(size_t)row * N + ccol0 + 16] = (__bf16)v1;
                } else {
                    C[(size_t)row * N + ccol0]      = v0;
                    C[(size_t)row * N + ccol0 + 16] = v1;
                }
            }
        }
    }
}

// ---------------- fused K+V GEMM, double-buffered gload_lds (V transposed out) ----------------
__global__ __launch_bounds__(256) void gemm_kv_kernel(
    const __bf16* __restrict__ A,
    const __bf16* __restrict__ Wh, const __bf16* __restrict__ Wl,
    const float* __restrict__ biasK, const float* __restrict__ biasV,
    uint32_t* __restrict__ Kpk, uint32_t* __restrict__ Vt) {
    constexpr int BM = 128, BN = 64, BK = 32, K = 512;
    constexpr int ASZ = BM * BK;
    constexpr int WSZ = BN * BK;
    __shared__ alignas(16) __bf16 Ahs[2][ASZ];
    __shared__ alignas(16) __bf16 Bhs[2][WSZ];
    __shared__ alignas(16) __bf16 Bls[2][WSZ];

    const int GM = (M_ + BM - 1) / BM;
    const int nwg = gridDim.x;
    int bid = blockIdx.x;
    {
        int q = nwg >> 3, r = nwg & 7;
        int xcd = bid & 7, pos = bid >> 3;
        bid = (xcd < r) ? xcd * (q + 1) + pos
                        : r * (q + 1) + (xcd - r) * q + pos;
    }
    const int bn = bid / GM;
    const int bm = bid % GM;
    const int m0 = bm * BM;
    const int n0 = bn * BN;

    const int tid  = threadIdx.x;
    const int lane = tid & 63;
    const int wv   = tid >> 6;
    const int wr   = wv >> 1;
    const int wc   = wv & 1;
    const int fr   = lane & 15;
    const int fq   = lane >> 4;
    const int fq8  = fq * 8;
    const int mb   = wr * 64;
    const int nb   = wc * 32;

    const int acol = (lane & 3) * 8;
    int ar0 = m0 + wv * 32 + (lane >> 2);
    int ar1 = ar0 + 16;
    if (ar0 > M_ - 1) ar0 = M_ - 1;
    if (ar1 > M_ - 1) ar1 = M_ - 1;
    const __bf16* aG0 = A + (size_t)ar0 * K + acol;
    const __bf16* aG1 = A + (size_t)ar1 * K + acol;
    const int aLoff0 = wv * 1024 + lane * 8;
    const int aLoff1 = aLoff0 + 512;
    const int wrow = n0 + wv * 16 + (lane >> 2);
    const __bf16* wGh = Wh + (size_t)wrow * K + acol;
    const __bf16* wGl = Wl + (size_t)wrow * K + acol;
    const int wLoff = wv * 512 + lane * 8;

    f32x4 acc[4][2];
#pragma unroll
    for (int i = 0; i < 4; ++i)
#pragma unroll
        for (int j = 0; j < 2; ++j) acc[i][j] = (f32x4){0.f, 0.f, 0.f, 0.f};

    const int nk = K / BK;
    gload16(aG0, &Ahs[0][aLoff0]);
    gload16(aG1, &Ahs[0][aLoff1]);
    gload16(wGh, &Bhs[0][wLoff]);
    gload16(wGl, &Bls[0][wLoff]);

    int buf = 0;
    for (int kt = 0; kt < nk; ++kt) {
        __syncthreads();

        if (kt + 1 < nk) {
            const int k1 = (kt + 1) * BK;
            const int nb2 = buf ^ 1;
            gload16(aG0 + k1, &Ahs[nb2][aLoff0]);
            gload16(aG1 + k1, &Ahs[nb2][aLoff1]);
            gload16(wGh + k1, &Bhs[nb2][wLoff]);
            gload16(wGl + k1, &Bls[nb2][wLoff]);
        }

        bf16x8 ah[4], bh[2], bl[2];
#pragma unroll
        for (int i = 0; i < 4; ++i)
            ah[i] = *(bf16x8*)&Ahs[buf][(mb + i * 16 + fr) * BK + fq8];
#pragma unroll
        for (int j = 0; j < 2; ++j) {
            bh[j] = *(bf16x8*)&Bhs[buf][(nb + j * 16 + fr) * BK + fq8];
            bl[j] = *(bf16x8*)&Bls[buf][(nb + j * 16 + fr) * BK + fq8];
        }
#pragma unroll
        for (int i = 0; i < 4; ++i)
#pragma unroll
            for (int j = 0; j < 2; ++j)
                acc[i][j] = __builtin_amdgcn_mfma_f32_16x16x32_bf16(ah[i], bh[j], acc[i][j], 0, 0, 0);
#pragma unroll
        for (int i = 0; i < 4; ++i)
#pragma unroll
            for (int j = 0; j < 2; ++j)
                acc[i][j] = __builtin_amdgcn_mfma_f32_16x16x32_bf16(ah[i], bl[j], acc[i][j], 0, 0, 0);
        buf ^= 1;
    }

    const int ccol0 = n0 + nb + fr;
    if (n0 < 512) {
        const float b0 = biasK[ccol0];
        const float b1 = biasK[ccol0 + 16];
#pragma unroll
        for (int i = 0; i < 4; ++i) {
#pragma unroll
            for (int r = 0; r < 4; ++r) {
                int row = m0 + mb + i * 16 + fq * 4 + r;
                if (row < M_) {
                    Kpk[(size_t)row * 512 + ccol0]      = pkhl(acc[i][0][r] + b0);
                    Kpk[(size_t)row * 512 + ccol0 + 16] = pkhl(acc[i][1][r] + b1);
                }
            }
        }
    } else {
        const int cv = ccol0 - 512;
        const int h2 = cv >> 6, d2 = cv & 63;
        const float b0 = biasV[cv];
        const float b1 = biasV[cv + 16];
#pragma unroll
        for (int i = 0; i < 4; ++i) {
#pragma unroll
            for (int r = 0; r < 4; ++r) {
                int row = m0 + mb + i * 16 + fq * 4 + r;
                if (row < M_) {
                    int b2 = row / L_;
                    int l2 = row - b2 * L_;
                    size_t vb = (size_t)(b2 * H_ + h2) * DH_ * LP_;
                    Vt[vb + (size_t)d2 * LP_ + l2]        = pkhl(acc[i][0][r] + b0);
                    Vt[vb + (size_t)(d2 + 16) * LP_ + l2] = pkhl(acc[i][1][r] + b1);
                }
            }
        }
    }
}

// ---------------- MFMA flash attention, split-K, reduced precision ----------------
// QK^T: 1-pass bf16 (hi only). PV: 2-pass, P_hi x (V_hi + V_lo).
__global__ __launch_bounds__(256) void attn_mfma_kernel(
    const uint32_t* __restrict__ Qpk, const uint32_t* __restrict__ Kpk,
    const uint32_t* __restrict__ Vtpk, float* __restrict__ Opart,
    float* __restrict__ ml) {
    constexpr int LDU = 68;
    constexpr int NT = (L_ + 63) / 64;        // 17
    __shared__ alignas(16) uint32_t Kls[64][LDU];
    __shared__ alignas(16) uint32_t Vls[64][LDU];

    const int tid  = threadIdx.x;
    const int lane = tid & 63;
    const int wv   = tid >> 6;
    const int fr   = lane & 15;
    const int fq   = lane >> 4;
    const int fq8  = fq * 8;

    int bid = blockIdx.x;
    int swz = (bid & 7) * (NSPLIT_ * NQT_ * H_ * B_ / 8) + (bid >> 3);
    const int s   = swz / (NQT_ * H_ * B_);
    int rem = swz - s * (NQT_ * H_ * B_);
    const int qt = rem % NQT_;
    const int bh = rem / NQT_;
    const int h = bh & 7, b = bh >> 3;
    const int q0 = qt * 128 + wv * 32;
    const int T0 = (s == 0) ? 0 : 9;
    const int T1 = (s == 0) ? 9 : NT;
    const size_t obase = (size_t)b * L_ * D_ + h * DH_;

    bf16x8 bqh[2][2];
#pragma unroll
    for (int g = 0; g < 2; ++g) {
        int gq = q0 + 16 * g + fr; if (gq > L_ - 1) gq = L_ - 1;
        const uint32_t* qrow = Qpk + (size_t)(b * L_ + gq) * D_ + h * DH_;
#pragma unroll
        for (int ss = 0; ss < 2; ++ss) {
            uint32_t r[8];
            *(u32x4*)&r[0] = *(const u32x4*)&qrow[ss * 32 + fq8];
            *(u32x4*)&r[4] = *(const u32x4*)&qrow[ss * 32 + fq8 + 4];
            bqh[g][ss] = unpk8h(r);
        }
    }

    float m[2] = {-1e30f, -1e30f};
    float lsum[2] = {0.f, 0.f};
    f32x4 oA[2][4];
#pragma unroll
    for (int g = 0; g < 2; ++g)
#pragma unroll
        for (int c = 0; c < 4; ++c) oA[g][c] = (f32x4){0.f, 0.f, 0.f, 0.f};

    const int sr = tid >> 2;
    const int sc = (tid & 3) * 16;
    const size_t kRowBase = (size_t)(b * L_) * D_ + h * DH_ + sc;
    const size_t vRowBase = ((size_t)bh * DH_ + sr) * LP_ + sc;

    u32x4 kR[4], vR[4];
    {
        int gr = T0 * 64 + sr; if (gr > L_ - 1) gr = L_ - 1;
        const uint32_t* kp = Kpk + kRowBase + (size_t)gr * D_;
        const uint32_t* vp = Vtpk + vRowBase + T0 * 64;
#pragma unroll
        for (int i = 0; i < 4; ++i) { kR[i] = *(const u32x4*)&kp[i * 4]; vR[i] = *(const u32x4*)&vp[i * 4]; }
#pragma unroll
        for (int i = 0; i < 4; ++i) {
            *(u32x4*)&Kls[sr][sc + i * 4] = kR[i];
            *(u32x4*)&Vls[sr][sc + i * 4] = vR[i];
        }
    }

    for (int t = T0; t < T1; ++t) {
        const int kt = t * 64;
        __syncthreads();

        if (t + 1 < T1) {
            int gr = kt + 64 + sr; if (gr > L_ - 1) gr = L_ - 1;
            const uint32_t* kp = Kpk + kRowBase + (size_t)gr * D_;
            const uint32_t* vp = Vtpk + vRowBase + (kt + 64);
#pragma unroll
            for (int i = 0; i < 4; ++i) { kR[i] = *(const u32x4*)&kp[i * 4]; vR[i] = *(const u32x4*)&vp[i * 4]; }
        }

        float p0[4][4], p1[4][4];
#pragma unroll
        for (int c = 0; c < 4; ++c) {
            const int row = 16 * c + fr;
            uint32_t r[8];
            *(u32x4*)&r[0] = *(u32x4*)&Kls[row][fq8];
            *(u32x4*)&r[4] = *(u32x4*)&Kls[row][fq8 + 4];
            bf16x8 ah0 = unpk8h(r);
            *(u32x4*)&r[0] = *(u32x4*)&Kls[row][32 + fq8];
            *(u32x4*)&r[4] = *(u32x4*)&Kls[row][32 + fq8 + 4];
            bf16x8 ah1 = unpk8h(r);
#pragma unroll
            for (int g = 0; g < 2; ++g) {
                f32x4 sacc = (f32x4){0.f, 0.f, 0.f, 0.f};
                sacc = __builtin_amdgcn_mfma_f32_16x16x32_bf16(ah0, bqh[g][0], sacc, 0, 0, 0);
                sacc = __builtin_amdgcn_mfma_f32_16x16x32_bf16(ah1, bqh[g][1], sacc, 0, 0, 0);
#pragma unroll
                for (int rr = 0; rr < 4; ++rr) {
                    int k = kt + 16 * c + 4 * fq + rr;
                    float val = (k < L_) ? sacc[rr] * SCALE_ : -1e30f;
                    if (g == 0) p0[c][rr] = val; else p1[c][rr] = val;
                }
            }
        }

        bf16x8 pah[2][2];
#pragma unroll
        for (int g = 0; g < 2; ++g) {
            float (*p)[4] = (g == 0) ? p0 : p1;
            float t0 = p[0][0];
#pragma unroll
            for (int c = 0; c < 4; ++c)
#pragma unroll
                for (int rr = 0; rr < 4; ++rr) t0 = fmaxf(t0, p[c][rr]);
            t0 = fmaxf(t0, __shfl_xor(t0, 16));
            t0 = fmaxf(t0, __shfl_xor(t0, 32));
            float mn = fmaxf(m[g], t0);
            float sclq = __expf(m[g] - mn);
            m[g] = mn;
            float ls = 0.f;
#pragma unroll
            for (int c = 0; c < 4; ++c)
#pragma unroll
                for (int rr = 0; rr < 4; ++rr) {
                    float e = __expf(p[c][rr] - mn);
                    p[c][rr] = e;
                    ls += e;
                }
            ls += __shfl_xor(ls, 16);
            ls += __shfl_xor(ls, 32);
            lsum[g] = lsum[g] * sclq + ls;
#pragma unroll
            for (int rr = 0; rr < 4; ++rr) {
                float sO = __shfl(sclq, 4 * fq + rr);
#pragma unroll
                for (int c2 = 0; c2 < 4; ++c2) oA[g][c2][rr] *= sO;
            }

            uint32_t pqh[4][2];
#pragma unroll
            for (int c = 0; c < 4; ++c) {
                pqh[c][0] = pk2f(p[c][0], p[c][1]);
                pqh[c][1] = pk2f(p[c][2], p[c][3]);
            }
            const int src0 = fr + ((fq & 1) << 5);
            const int src1 = src0 + 16;
            const bool sel = (fq >> 1) != 0;
#pragma unroll
            for (int ss = 0; ss < 2; ++ss) {
                const int c0 = 2 * ss, c1 = 2 * ss + 1;
                uint32_t A0 = (uint32_t)__shfl((int)pqh[c0][0], src0);
                uint32_t A1 = (uint32_t)__shfl((int)pqh[c0][1], src0);
                uint32_t A2 = (uint32_t)__shfl((int)pqh[c0][0], src1);
                uint32_t A3 = (uint32_t)__shfl((int)pqh[c0][1], src1);
                uint32_t B0 = (uint32_t)__shfl((int)pqh[c1][0], src0);
                uint32_t B1 = (uint32_t)__shfl((int)pqh[c1][1], src0);
                uint32_t B2 = (uint32_t)__shfl((int)pqh[c1][0], src1);
                uint32_t B3 = (uint32_t)__shfl((int)pqh[c1][1], src1);
                U4 uh;
                uh.u[0] = sel ? B0 : A0; uh.u[1] = sel ? B1 : A1;
                uh.u[2] = sel ? B2 : A2; uh.u[3] = sel ? B3 : A3;
                pah[g][ss] = uh.f;
            }
        }

#pragma unroll
        for (int c2 = 0; c2 < 4; ++c2) {
            const int row = 16 * c2 + fr;
            uint32_t r[8];
            bf16x8 vh0, vl0, vh1, vl1;
            *(u32x4*)&r[0] = *(u32x4*)&Vls[row][fq8];
            *(u32x4*)&r[4] = *(u32x4*)&Vls[row][fq8 + 4];
            unpk8(r, vh0, vl0);
            *(u32x4*)&r[0] = *(u32x4*)&Vls[row][32 + fq8];
            *(u32x4*)&r[4] = *(u32x4*)&Vls[row][32 + fq8 + 4];
            unpk8(r, vh1, vl1);
#pragma unroll
            for (int g = 0; g < 2; ++g) {
                f32x4 o = oA[g][c2];
                o = __builtin_amdgcn_mfma_f32_16x16x32_bf16(pah[g][0], vh0, o, 0, 0, 0);
                o = __builtin_amdgcn_mfma_f32_16x16x32_bf16(pah[g][1], vh1, o, 0, 0, 0);
                o = __builtin_amdgcn_mfma_f32_16x16x32_bf16(pah[g][0], vl0, o, 0, 0, 0);
                o = __builtin_amdgcn_mfma_f32_16x16x32_bf16(pah[g][1], vl1, o, 0, 0, 0);
                oA[g][c2] = o;
            }
        }

        __syncthreads();
        if (t + 1 < T1) {
#pragma unroll
            for (int i = 0; i < 4; ++i) {
                *(u32x4*)&Kls[sr][sc + i * 4] = kR[i];
                *(u32x4*)&Vls[sr][sc + i * 4] = vR[i];
            }
        }
    }

    float* Op = Opart + (size_t)s * M_ * D_;
#pragma unroll
    for (int g = 0; g < 2; ++g) {
#pragma unroll
        for (int rr = 0; rr < 4; ++rr) {
            int row = q0 + 16 * g + 4 * fq + rr;
            if (row < L_) {
#pragma unroll
                for (int c2 = 0; c2 < 4; ++c2)
                    Op[obase + (size_t)row * D_ + 16 * c2 + fr] = oA[g][c2][rr];
            }
        }
        if (fq == 0) {
            int qrow = q0 + 16 * g + fr;
            if (qrow < L_) {
                size_t mlidx = (((size_t)s * B_ + b) * H_ + h) * L_ + qrow;
                ml[mlidx * 2]     = m[g];
                ml[mlidx * 2 + 1] = lsum[g];
            }
        }
    }
}

// ---------------- merge split-K partials -> bf16 (Wo GEMM A-operand) ----------------
__global__ __launch_bounds__(256) void attn_merge_kernel(
    const float* __restrict__ Opart, const float* __restrict__ ml,
    __bf16* __restrict__ Out) {
    int idx = blockIdx.x * 256 + threadIdx.x;
    if (idx >= M_ * 64) return;
    int row = idx >> 6;
    int seg = idx & 63;
    int col0 = seg * 8;
    int h = col0 >> 6;
    int b = row / L_;
    int l = row - b * L_;
    size_t i0 = ((((size_t)0 * B_ + b) * H_ + h) * L_ + l) * 2;
    size_t i1 = ((((size_t)1 * B_ + b) * H_ + h) * L_ + l) * 2;
    float m0 = ml[i0], l0 = ml[i0 + 1];
    float m1 = ml[i1], l1 = ml[i1 + 1];
    float mm = fmaxf(m0, m1);
    float e0 = __expf(m0 - mm), e1 = __expf(m1 - mm);
    float inv = 1.f / (e0 * l0 + e1 * l1);
    float w0 = e0 * inv, w1 = e1 * inv;
    size_t base = (size_t)row * D_ + col0;
    const float* O0 = Opart;
    const float* O1 = Opart + (size_t)M_ * D_;
    float4 a0 = *(const float4*)&O0[base];
    float4 a1 = *(const float4*)&O0[base + 4];
    float4 c0 = *(const float4*)&O1[base];
    float4 c1 = *(const float4*)&O1[base + 4];
    float o0 = w0 * a0.x + w1 * c0.x, o1v = w0 * a0.y + w1 * c0.y;
    float o2 = w0 * a0.z + w1 * c0.z, o3 = w0 * a0.w + w1 * c0.w;
    float o4 = w0 * a1.x + w1 * c1.x, o5 = w0 * a1.y + w1 * c1.y;
    float o6 = w0 * a1.z + w1 * c1.z, o7 = w0 * a1.w + w1 * c1.w;
    U4 u;
    u.u[0] = pk2f(o0, o1v); u.u[1] = pk2f(o2, o3);
    u.u[2] = pk2f(o4, o5);  u.u[3] = pk2f(o6, o7);
    *(u32x4*)&Out[base] = *(u32x4*)&u.u[0];
}

// ---------------- fused residual add + LayerNorm (+ optional bf16-hi out) ----------------
template <bool HIOUT>
__global__ __launch_bounds__(256) void add_ln_kernel(
    const float* __restrict__ X, const float* __restrict__ Y,
    const float* __restrict__ g, const float* __restrict__ be,
    float* __restrict__ Out, __bf16* __restrict__ Oh) {
    int wave = threadIdx.x >> 6;
    int lane = threadIdx.x & 63;
    int row = blockIdx.x * 4 + wave;
    if (row >= M_) return;
    size_t base = (size_t)row * D_;
    int c0 = lane * 4, c1 = 256 + lane * 4;
    float4 xa = *(const float4*)&X[base + c0];
    float4 xb = *(const float4*)&X[base + c1];
    float4 ya = *(const float4*)&Y[base + c0];
    float4 yb = *(const float4*)&Y[base + c1];
    float v[8] = {xa.x + ya.x, xa.y + ya.y, xa.z + ya.z, xa.w + ya.w,
                  xb.x + yb.x, xb.y + yb.y, xb.z + yb.z, xb.w + yb.w};
    float s = 0.f, s2 = 0.f;
#pragma unroll
    for (int i = 0; i < 8; ++i) { s += v[i]; s2 = fmaf(v[i], v[i], s2); }
#pragma unroll
    for (int off = 32; off > 0; off >>= 1) {
        s  += __shfl_xor(s, off);
        s2 += __shfl_xor(s2, off);
    }
    float mean = s * (1.f / D_);
    float var  = s2 * (1.f / D_) - mean * mean;
    float rstd = rsqrtf(var + EPS_);
    float4 ga = *(const float4*)&g[c0];
    float4 gb = *(const float4*)&g[c1];
    float4 ba = *(const float4*)&be[c0];
    float4 bb = *(const float4*)&be[c1];
    float o[8];
    o[0] = (v[0] - mean) * rstd * ga.x + ba.x;
    o[1] = (v[1] - mean) * rstd * ga.y + ba.y;
    o[2] = (v[2] - mean) * rstd * ga.z + ba.z;
    o[3] = (v[3] - mean) * rstd * ga.w + ba.w;
    o[4] = (v[4] - mean) * rstd * gb.x + bb.x;
    o[5] = (v[5] - mean) * rstd * gb.y + bb.y;
    o[6] = (v[6] - mean) * rstd * gb.z + bb.z;
    o[7] = (v[7] - mean) * rstd * gb.w + bb.w;
    *(float4*)&Out[base + c0] = make_float4(o[0], o[1], o[2], o[3]);
    *(float4*)&Out[base + c1] = make_float4(o[4], o[5], o[6], o[7]);
    if (HIOUT) {
        bf16x4 h0, h1;
#pragma unroll
        for (int i = 0; i < 4; ++i) {
            h0[i] = (__bf16)o[i];
            h1[i] = (__bf16)o[4 + i];
        }
        *(bf16x4*)&Oh[base + c0] = h0;
        *(bf16x4*)&Oh[base + c1] = h1;
    }
}

// ---------------- launch ----------------
extern "C" void kernel_launch(void* const* d_in, const int* in_sizes, int n_in,
                              void* d_out, int out_size, void* d_ws, size_t ws_size,
                              hipStream_t stream) {
    const float* embed1 = (const float*)d_in[0];
    const float* embed2 = (const float*)d_in[1];
    const float* cls    = (const float*)d_in[2];
    const float* Wq = (const float*)d_in[3];
    const float* bq = (const float*)d_in[4];
    const float* Wk = (const float*)d_in[5];
    const float* bk = (const float*)d_in[6];
    const float* Wv = (const float*)d_in[7];
    const float* bv = (const float*)d_in[8];
    const float* Wo = (const float*)d_in[9];
    const float* bo = (const float*)d_in[10];
    const float* ln1g = (const float*)d_in[11];
    const float* ln1b = (const float*)d_in[12];
    const float* W1 = (const float*)d_in[13];
    const float* b1 = (const float*)d_in[14];
    const float* W2 = (const float*)d_in[15];
    const float* b2 = (const float*)d_in[16];
    const float* ln2g = (const float*)d_in[17];
    const float* ln2b = (const float*)d_in[18];

    const size_t SZ = (size_t)M_ * D_;        // 4,198,400 floats
    float* ws = (float*)d_ws;
    float* X   = ws;                           // [0,SZ) fp32 residual stream
    __bf16* Xh = (__bf16*)(ws + SZ);           // [SZ,1.5SZ) bf16-hi of X
    __bf16* X2h = (__bf16*)(ws + SZ + SZ / 2); // [1.5SZ,2SZ) bf16-hi of X2
    float* Tb  = ws + 2 * SZ;                  // [2SZ,3SZ): fp32 scratch (X2 setup, FFN2 out)
    __bf16* Tbh = (__bf16*)(ws + 2 * SZ + SZ / 2); // merge out (attn phase; Tb fp32 dead then)
    uint32_t* Qpk = (uint32_t*)(ws + 3 * SZ);  // packed hi|lo
    float* WoOut  = (float*)Qpk;               // aliases Qpk (dead after attn)
    uint32_t* Kpk = (uint32_t*)(ws + 4 * SZ);
    uint32_t* Vtpk = (uint32_t*)(ws + 5 * SZ); // [5SZ,~6.07SZ) attn phase
    __bf16* Hbh = (__bf16*)(ws + 5 * SZ);      // [5SZ,7SZ) bf16 [M,DFF] FFN phase (aliases Vtpk)
    float* mlBuf   = ws + 6 * SZ + SZ / 2;     // stats (attn phase) -- inside Hbh region, dead by FFN
    float* Opart   = ws + 7 * SZ;              // [7SZ,9SZ) 2 partial O (attn phase)
    __bf16* wreg = (__bf16*)(ws + 9 * SZ);     // weight hi/lo planes

    const size_t NQl = (size_t)D_ * D_;                // 262144 per layer
    const size_t NQ  = (size_t)NLAYER_ * NQl;          // 524288
    const size_t NF  = (size_t)NLAYER_ * DFF_ * D_;    // 2097152
    __bf16* Wqh  = wreg;           __bf16* Wql  = Wqh + NQ;
    __bf16* Wkvh = Wql + NQ;       __bf16* Wkvl = Wkvh + 2 * NQ;  // [NLAYER][1024][512]
    __bf16* Woh  = Wkvl + 2 * NQ;  __bf16* Wol  = Woh + NQ;
    __bf16* W1h  = Wol + NQ;       __bf16* W1l  = W1h + NF;
    __bf16* W2h  = W1l + NF;       __bf16* W2l  = W2h + NF;

    split_w_kernel<<<(int)(NQ / 4 + 255) / 256, 256, 0, stream>>>(Wq, Wqh, Wql, (int)(NQ / 4));
    split_w_kernel<<<(int)(NQ / 4 + 255) / 256, 256, 0, stream>>>(Wo, Woh, Wol, (int)(NQ / 4));
    split_w_kernel<<<(int)(NF / 4 + 255) / 256, 256, 0, stream>>>(W1, W1h, W1l, (int)(NF / 4));
    split_w_kernel<<<(int)(NF / 4 + 255) / 256, 256, 0, stream>>>(W2, W2h, W2l, (int)(NF / 4));
    for (int l = 0; l < NLAYER_; ++l) {
        split_w_kernel<<<(int)(NQl / 4 + 255) / 256, 256, 0, stream>>>(
            Wk + l * NQl, Wkvh + l * 2 * NQl, Wkvl + l * 2 * NQl, (int)(NQl / 4));
        split_w_kernel<<<(int)(NQl / 4 + 255) / 256, 256, 0, stream>>>(
            Wv + l * NQl, Wkvh + l * 2 * NQl + NQl, Wkvl + l * 2 * NQl + NQl, (int)(NQl / 4));
    }

    // build X (fp32, persistent) and X2 (fp32 in Tb scratch, converted once)
    float* X2tmp = Tb;
    write_cls_kernel<<<(B_ * D_) / 256, 256, 0, stream>>>(cls, X, X2tmp);
    transpose_embed_kernel<<<dim3(L0_ / 32, D_ / 32, B_), dim3(32, 8), 0, stream>>>(embed1, X);
    transpose_embed_kernel<<<dim3(L0_ / 32, D_ / 32, B_), dim3(32, 8), 0, stream>>>(embed2, X2tmp);
    tobf16_kernel<<<(int)(SZ / 4 + 255) / 256, 256, 0, stream>>>(X, Xh, (int)(SZ / 4));
    tobf16_kernel<<<(int)(SZ / 4 + 255) / 256, 256, 0, stream>>>(X2tmp, X2h, (int)(SZ / 4));

    const int GM = (M_ + 127) / 128;         // 65
    const int g512  = GM * (512 / 64);       // 520
    const int g1024 = GM * (1024 / 64);      // 1040
    const int g2048 = GM * (2048 / 64);      // 2080
    const int gpad  = (B_ * H_ * DH_ * (LP_ - L_) + 255) / 256;
    const int gmerge = (M_ * 64 + 255) / 256;

    for (int l = 0; l < NLAYER_; ++l) {
        const size_t oQ = (size_t)l * NQl;
        const size_t oF = (size_t)l * DFF_ * D_;

        gemm_mfma_kernel<false, 1><<<g512, 256, 0, stream>>>(
            Xh, Wqh + oQ, Wql + oQ, bq + l * D_, nullptr, Qpk, nullptr, M_, D_, D_);
        gemm_kv_kernel<<<g1024, 256, 0, stream>>>(
            X2h, Wkvh + l * 2 * NQl, Wkvl + l * 2 * NQl,
            bk + l * D_, bv + l * D_, Kpk, Vtpk);
        zero_vt_pad_kernel<<<gpad, 256, 0, stream>>>(Vtpk);

        attn_mfma_kernel<<<NSPLIT_ * NQT_ * H_ * B_, 256, 0, stream>>>(
            Qpk, Kpk, Vtpk, Opart, mlBuf);
        attn_merge_kernel<<<gmerge, 256, 0, stream>>>(Opart, mlBuf, Tbh);

        gemm_mfma_kernel<false, 0><<<g512, 256, 0, stream>>>(
            Tbh, Woh + oQ, Wol + oQ, bo + l * D_, WoOut, nullptr, nullptr, M_, D_, D_);

        add_ln_kernel<true><<<(M_ + 3) / 4, 256, 0, stream>>>(
            X, WoOut, ln1g + l * D_, ln1b + l * D_, X, Xh);

        gemm_mfma_kernel<true, 2><<<g2048, 256, 0, stream>>>(
            Xh, W1h + oF, W1l + oF, b1 + l * DFF_, nullptr, nullptr, Hbh, M_, DFF_, D_);
        gemm_mfma_kernel<false, 0><<<g512, 256, 0, stream>>>(
            Hbh, W2h + oF, W2l + oF, b2 + l * D_, Tb, nullptr, nullptr, M_, D_, DFF_);

        if (l == NLAYER_ - 1) {
            add_ln_kernel<false><<<(M_ + 3) / 4, 256, 0, stream>>>(
                X, Tb, ln2g + l * D_, ln2b + l * D_, (float*)d_out, nullptr);
        } else {
            add_ln_kernel<true><<<(M_ + 3) / 4, 256, 0, stream>>>(
                X, Tb, ln2g + l * D_, ln2b + l * D_, X, Xh);
        }
    }
}

// Round 19
// 684.132 us; speedup vs baseline: 1.0744x; 1.0744x over previous
//
#include <hip/hip_runtime.h>
#include <hip/hip_bf16.h>

// ---------------- problem constants ----------------
constexpr int B_   = 8;
constexpr int D_   = 512;
constexpr int L0_  = 1024;
constexpr int L_   = 1025;          // L0 + cls
constexpr int H_   = 8;
constexpr int DH_  = 64;
constexpr int DFF_ = 2048;
constexpr int NLAYER_ = 2;
constexpr int M_   = B_ * L_;       // 8200 rows
constexpr int LP_  = 1088;          // padded L for Vt (17*64)
constexpr int NQT_ = 9;             // ceil(L/128) attn q-tiles
constexpr int NSPLIT_ = 2;          // K-range partitions (flash-decoding)
constexpr float EPS_   = 1e-6f;
constexpr float SCALE_ = 0.125f;    // 1/sqrt(64)

#define DEV_INLINE __device__ __forceinline__

typedef __attribute__((ext_vector_type(8))) __bf16 bf16x8;
typedef __attribute__((ext_vector_type(4))) __bf16 bf16x4;
typedef __attribute__((ext_vector_type(4))) float  f32x4;
typedef __attribute__((ext_vector_type(4))) unsigned int u32x4;

union U4 { uint32_t u[4]; bf16x8 f; };

DEV_INLINE float gelu_exact(float x) {
    return 0.5f * x * (1.f + erff(x * 0.70710678118654752f));
}

struct bfpair { __bf16 h, l; };
DEV_INLINE bfpair split_bf(float v) {
    bfpair p;
    p.h = (__bf16)v;
    p.l = (__bf16)(v - (float)p.h);
    return p;
}
DEV_INLINE uint16_t bfbits(float v) {
    __bf16 h = (__bf16)v;
    return __builtin_bit_cast(uint16_t, h);
}
DEV_INLINE uint32_t pk2f(float a, float b) {
    return (uint32_t)bfbits(a) | ((uint32_t)bfbits(b) << 16);
}
DEV_INLINE uint32_t pkhl(float v) {
    bfpair s = split_bf(v);
    return (uint32_t)__builtin_bit_cast(uint16_t, s.h)
         | ((uint32_t)__builtin_bit_cast(uint16_t, s.l) << 16);
}
// hi plane only
DEV_INLINE bf16x8 unpk8h(const uint32_t* r) {
    U4 uh;
#pragma unroll
    for (int i = 0; i < 4; ++i) {
        uint32_t a = r[2 * i], b = r[2 * i + 1];
        uh.u[i] = (a & 0xffffu) | (b << 16);
    }
    return uh.f;
}

// ---------------- fp32 -> bf16 hi/lo plane split (weights) ----------------
__global__ __launch_bounds__(256) void split_w_kernel(
    const float* __restrict__ src, __bf16* __restrict__ hi,
    __bf16* __restrict__ lo, int n4) {
    int i = blockIdx.x * 256 + threadIdx.x;
    if (i >= n4) return;
    float4 v = *(const float4*)&src[i * 4];
    bf16x4 h, l;
    bfpair p0 = split_bf(v.x); h[0] = p0.h; l[0] = p0.l;
    bfpair p1 = split_bf(v.y); h[1] = p1.h; l[1] = p1.l;
    bfpair p2 = split_bf(v.z); h[2] = p2.h; l[2] = p2.l;
    bfpair p3 = split_bf(v.w); h[3] = p3.h; l[3] = p3.l;
    *(bf16x4*)&hi[i * 4] = h;
    *(bf16x4*)&lo[i * 4] = l;
}

// ---------------- fp32 -> bf16 (hi only) ----------------
__global__ __launch_bounds__(256) void tobf16_kernel(
    const float* __restrict__ src, __bf16* __restrict__ dst, int n4) {
    int i = blockIdx.x * 256 + threadIdx.x;
    if (i >= n4) return;
    float4 v = *(const float4*)&src[i * 4];
    bf16x4 h;
    h[0] = (__bf16)v.x; h[1] = (__bf16)v.y;
    h[2] = (__bf16)v.z; h[3] = (__bf16)v.w;
    *(bf16x4*)&dst[i * 4] = h;
}

// ---------------- zero Vt pad tokens (l = L_..LP_-1) ----------------
// CRITICAL: pad tokens feed PV MFMA with P=0; garbage bits there can alias
// bf16 Inf/NaN and 0*Inf = NaN (R10 failure). Must be zeroed every layer.
__global__ __launch_bounds__(256) void zero_vt_pad_kernel(uint32_t* __restrict__ Vt) {
    constexpr int PAD = LP_ - L_;                 // 63
    int idx = blockIdx.x * 256 + threadIdx.x;
    int total = B_ * H_ * DH_ * PAD;
    if (idx >= total) return;
    int row = idx / PAD;
    int c   = idx - row * PAD;
    Vt[(size_t)row * LP_ + L_ + c] = 0u;
}

// ---------------- build x1/x2 ----------------
__global__ __launch_bounds__(256) void write_cls_kernel(
    const float* __restrict__ cls, float* __restrict__ X1, float* __restrict__ X2) {
    int idx = blockIdx.x * 256 + threadIdx.x;
    int b = idx >> 9;
    int d = idx & 511;
    float v = cls[d];
    X1[(size_t)b * L_ * D_ + d] = v;
    X2[(size_t)b * L_ * D_ + d] = v;
}

// embed [B, D, L0] -> X rows 1..L0
__global__ __launch_bounds__(256) void transpose_embed_kernel(
    const float* __restrict__ e, float* __restrict__ X) {
    __shared__ float tile[32][33];
    int b  = blockIdx.z;
    int i0 = blockIdx.x * 32;
    int d0 = blockIdx.y * 32;
    int tx = threadIdx.x;
    int ty = threadIdx.y;
#pragma unroll
    for (int j = 0; j < 32; j += 8)
        tile[ty + j][tx] = e[((size_t)b * D_ + d0 + ty + j) * L0_ + i0 + tx];
    __syncthreads();
#pragma unroll
    for (int j = 0; j < 32; j += 8)
        X[((size_t)b * L_ + 1 + i0 + ty + j) * D_ + d0 + tx] = tile[tx][ty + j];
}

// ---------------- 2-pass MFMA GEMM (bf16-hi A in global, W pre-split) ----------------
// R16 structure: reg-staging with next-tile prefetch (best measured).
// OUTMODE: 0 = fp32 C, 1 = packed u32 (hi|lo) Cpk, 2 = bf16-hi Ch.
template <bool GELU, int OUTMODE>
__global__ __launch_bounds__(256) void gemm_mfma_kernel(
    const __bf16* __restrict__ A,
    const __bf16* __restrict__ Wh, const __bf16* __restrict__ Wl,
    const float* __restrict__ bias, float* __restrict__ C,
    uint32_t* __restrict__ Cpk, __bf16* __restrict__ Ch,
    int M, int N, int K) {
    constexpr int BM = 128, BN = 64, BK = 32;
    constexpr int LDK = BK + 8;
    __shared__ alignas(16) __bf16 Ahs[BM][LDK];
    __shared__ alignas(16) __bf16 Bhs[BN][LDK];
    __shared__ alignas(16) __bf16 Bls[BN][LDK];

    const int GM = (M + BM - 1) / BM;
    const int nwg = gridDim.x;
    int bid = blockIdx.x;
    {
        int q = nwg >> 3, r = nwg & 7;
        int xcd = bid & 7, pos = bid >> 3;
        bid = (xcd < r) ? xcd * (q + 1) + pos
                        : r * (q + 1) + (xcd - r) * q + pos;
    }
    const int bn = bid / GM;
    const int bm = bid % GM;
    const int m0 = bm * BM;
    const int n0 = bn * BN;

    const int tid  = threadIdx.x;
    const int lane = tid & 63;
    const int wv   = tid >> 6;
    const int wr   = wv >> 1;
    const int wc   = wv & 1;
    const int fr   = lane & 15;
    const int fq   = lane >> 4;
    const int fq8  = fq * 8;
    const int mb   = wr * 64;
    const int nb   = wc * 32;

    // A staging: 128 rows x 32 bf16 = 512 x 16B chunks; 2 per thread
    const int srow = tid >> 2;          // 0..63
    const int scol = (tid & 3) * 8;     // bf16 col
    size_t aOff[2];
#pragma unroll
    for (int rep = 0; rep < 2; ++rep) {
        int r = m0 + srow + rep * 64;
        if (r > M - 1) r = M - 1;
        aOff[rep] = (size_t)r * K + scol;
    }
    const int swr = tid >> 2;
    const int swq = tid & 3;
    const size_t wOff = (size_t)(n0 + swr) * K + swq * 8;

    f32x4 acc[4][2];
#pragma unroll
    for (int i = 0; i < 4; ++i)
#pragma unroll
        for (int j = 0; j < 2; ++j) acc[i][j] = (f32x4){0.f, 0.f, 0.f, 0.f};

    const int nk = K / BK;
    u32x4 aR[2], wRh, wRl;
#pragma unroll
    for (int rep = 0; rep < 2; ++rep) aR[rep] = *(const u32x4*)&A[aOff[rep]];
    wRh = *(const u32x4*)&Wh[wOff];
    wRl = *(const u32x4*)&Wl[wOff];

    for (int kt = 0; kt < nk; ++kt) {
#pragma unroll
        for (int rep = 0; rep < 2; ++rep)
            *(u32x4*)&Ahs[srow + rep * 64][scol] = aR[rep];
        *(u32x4*)&Bhs[swr][swq * 8] = wRh;
        *(u32x4*)&Bls[swr][swq * 8] = wRl;
        __syncthreads();

        if (kt + 1 < nk) {
            int k0 = (kt + 1) * BK;
#pragma unroll
            for (int rep = 0; rep < 2; ++rep) aR[rep] = *(const u32x4*)&A[aOff[rep] + k0];
            wRh = *(const u32x4*)&Wh[wOff + k0];
            wRl = *(const u32x4*)&Wl[wOff + k0];
        }

        bf16x8 ah[4], bh[2], bl[2];
#pragma unroll
        for (int i = 0; i < 4; ++i)
            ah[i] = *(bf16x8*)&Ahs[mb + i * 16 + fr][fq8];
#pragma unroll
        for (int j = 0; j < 2; ++j) {
            bh[j] = *(bf16x8*)&Bhs[nb + j * 16 + fr][fq8];
            bl[j] = *(bf16x8*)&Bls[nb + j * 16 + fr][fq8];
        }
#pragma unroll
        for (int i = 0; i < 4; ++i)
#pragma unroll
            for (int j = 0; j < 2; ++j)
                acc[i][j] = __builtin_amdgcn_mfma_f32_16x16x32_bf16(ah[i], bh[j], acc[i][j], 0, 0, 0);
#pragma unroll
        for (int i = 0; i < 4; ++i)
#pragma unroll
            for (int j = 0; j < 2; ++j)
                acc[i][j] = __builtin_amdgcn_mfma_f32_16x16x32_bf16(ah[i], bl[j], acc[i][j], 0, 0, 0);
        __syncthreads();
    }

    const int ccol0 = n0 + nb + fr;
    const float b0 = bias[ccol0];
    const float b1 = bias[ccol0 + 16];
#pragma unroll
    for (int i = 0; i < 4; ++i) {
#pragma unroll
        for (int r = 0; r < 4; ++r) {
            int row = m0 + mb + i * 16 + fq * 4 + r;
            if (row < M) {
                float v0 = acc[i][0][r] + b0;
                float v1 = acc[i][1][r] + b1;
                if (GELU) { v0 = gelu_exact(v0); v1 = gelu_exact(v1); }
                if (OUTMODE == 1) {
                    Cpk[(size_t)row * N + ccol0]      = pkhl(v0);
                    Cpk[(size_t)row * N + ccol0 + 16] = pkhl(v1);
                } else if (OUTMODE == 2) {
                    Ch[(size_t)row * N + ccol0]      = (__bf16)v0;
                    Ch[(size_t)row * N + ccol0 + 16] = (__bf16)v1;
                } else {
                    C[(size_t)row * N + ccol0]      = v0;
                    C[(size_t)row * N + ccol0 + 16] = v1;
                }
            }
        }
    }
}

// ---------------- fused K+V GEMM, 2-pass, bf16 A (V stored transposed) ----------------
__global__ __launch_bounds__(256) void gemm_kv_kernel(
    const __bf16* __restrict__ A,
    const __bf16* __restrict__ Wh, const __bf16* __restrict__ Wl,
    const float* __restrict__ biasK, const float* __restrict__ biasV,
    uint32_t* __restrict__ Kpk, uint32_t* __restrict__ Vt) {
    constexpr int BM = 128, BN = 64, BK = 32, K = 512;
    constexpr int LDK = BK + 8;
    __shared__ alignas(16) __bf16 Ahs[BM][LDK];
    __shared__ alignas(16) __bf16 Bhs[BN][LDK];
    __shared__ alignas(16) __bf16 Bls[BN][LDK];

    const int GM = (M_ + BM - 1) / BM;
    const int nwg = gridDim.x;
    int bid = blockIdx.x;
    {
        int q = nwg >> 3, r = nwg & 7;
        int xcd = bid & 7, pos = bid >> 3;
        bid = (xcd < r) ? xcd * (q + 1) + pos
                        : r * (q + 1) + (xcd - r) * q + pos;
    }
    const int bn = bid / GM;
    const int bm = bid % GM;
    const int m0 = bm * BM;
    const int n0 = bn * BN;

    const int tid  = threadIdx.x;
    const int lane = tid & 63;
    const int wv   = tid >> 6;
    const int wr   = wv >> 1;
    const int wc   = wv & 1;
    const int fr   = lane & 15;
    const int fq   = lane >> 4;
    const int fq8  = fq * 8;
    const int mb   = wr * 64;
    const int nb   = wc * 32;

    const int srow = tid >> 2;
    const int scol = (tid & 3) * 8;
    size_t aOff[2];
#pragma unroll
    for (int rep = 0; rep < 2; ++rep) {
        int r = m0 + srow + rep * 64;
        if (r > M_ - 1) r = M_ - 1;
        aOff[rep] = (size_t)r * K + scol;
    }
    const int swr = tid >> 2;
    const int swq = tid & 3;
    const size_t wOff = (size_t)(n0 + swr) * K + swq * 8;

    f32x4 acc[4][2];
#pragma unroll
    for (int i = 0; i < 4; ++i)
#pragma unroll
        for (int j = 0; j < 2; ++j) acc[i][j] = (f32x4){0.f, 0.f, 0.f, 0.f};

    const int nk = K / BK;
    u32x4 aR[2], wRh, wRl;
#pragma unroll
    for (int rep = 0; rep < 2; ++rep) aR[rep] = *(const u32x4*)&A[aOff[rep]];
    wRh = *(const u32x4*)&Wh[wOff];
    wRl = *(const u32x4*)&Wl[wOff];

    for (int kt = 0; kt < nk; ++kt) {
#pragma unroll
        for (int rep = 0; rep < 2; ++rep)
            *(u32x4*)&Ahs[srow + rep * 64][scol] = aR[rep];
        *(u32x4*)&Bhs[swr][swq * 8] = wRh;
        *(u32x4*)&Bls[swr][swq * 8] = wRl;
        __syncthreads();

        if (kt + 1 < nk) {
            int k0 = (kt + 1) * BK;
#pragma unroll
            for (int rep = 0; rep < 2; ++rep) aR[rep] = *(const u32x4*)&A[aOff[rep] + k0];
            wRh = *(const u32x4*)&Wh[wOff + k0];
            wRl = *(const u32x4*)&Wl[wOff + k0];
        }

        bf16x8 ah[4], bh[2], bl[2];
#pragma unroll
        for (int i = 0; i < 4; ++i)
            ah[i] = *(bf16x8*)&Ahs[mb + i * 16 + fr][fq8];
#pragma unroll
        for (int j = 0; j < 2; ++j) {
            bh[j] = *(bf16x8*)&Bhs[nb + j * 16 + fr][fq8];
            bl[j] = *(bf16x8*)&Bls[nb + j * 16 + fr][fq8];
        }
#pragma unroll
        for (int i = 0; i < 4; ++i)
#pragma unroll
            for (int j = 0; j < 2; ++j)
                acc[i][j] = __builtin_amdgcn_mfma_f32_16x16x32_bf16(ah[i], bh[j], acc[i][j], 0, 0, 0);
#pragma unroll
        for (int i = 0; i < 4; ++i)
#pragma unroll
            for (int j = 0; j < 2; ++j)
                acc[i][j] = __builtin_amdgcn_mfma_f32_16x16x32_bf16(ah[i], bl[j], acc[i][j], 0, 0, 0);
        __syncthreads();
    }

    const int ccol0 = n0 + nb + fr;
    if (n0 < 512) {
        const float b0 = biasK[ccol0];
        const float b1 = biasK[ccol0 + 16];
#pragma unroll
        for (int i = 0; i < 4; ++i) {
#pragma unroll
            for (int r = 0; r < 4; ++r) {
                int row = m0 + mb + i * 16 + fq * 4 + r;
                if (row < M_) {
                    Kpk[(size_t)row * 512 + ccol0]      = pkhl(acc[i][0][r] + b0);
                    Kpk[(size_t)row * 512 + ccol0 + 16] = pkhl(acc[i][1][r] + b1);
                }
            }
        }
    } else {
        const int cv = ccol0 - 512;
        const int h2 = cv >> 6, d2 = cv & 63;
        const float b0 = biasV[cv];
        const float b1 = biasV[cv + 16];
#pragma unroll
        for (int i = 0; i < 4; ++i) {
#pragma unroll
            for (int r = 0; r < 4; ++r) {
                int row = m0 + mb + i * 16 + fq * 4 + r;
                if (row < M_) {
                    int b2 = row / L_;
                    int l2 = row - b2 * L_;
                    size_t vb = (size_t)(b2 * H_ + h2) * DH_ * LP_;
                    Vt[vb + (size_t)d2 * LP_ + l2]        = pkhl(acc[i][0][r] + b0);
                    Vt[vb + (size_t)(d2 + 16) * LP_ + l2] = pkhl(acc[i][1][r] + b1);
                }
            }
        }
    }
}

// ---------------- MFMA flash attention, split-K, reduced precision ----------------
// QK^T: 1-pass bf16 (hi only). PV: 1-pass, P_hi x V_hi (V_lo ~2^-9 rel, dropped).
__global__ __launch_bounds__(256) void attn_mfma_kernel(
    const uint32_t* __restrict__ Qpk, const uint32_t* __restrict__ Kpk,
    const uint32_t* __restrict__ Vtpk, float* __restrict__ Opart,
    float* __restrict__ ml) {
    constexpr int LDU = 68;
    constexpr int NT = (L_ + 63) / 64;        // 17
    __shared__ alignas(16) uint32_t Kls[64][LDU];
    __shared__ alignas(16) uint32_t Vls[64][LDU];

    const int tid  = threadIdx.x;
    const int lane = tid & 63;
    const int wv   = tid >> 6;
    const int fr   = lane & 15;
    const int fq   = lane >> 4;
    const int fq8  = fq * 8;

    int bid = blockIdx.x;
    int swz = (bid & 7) * (NSPLIT_ * NQT_ * H_ * B_ / 8) + (bid >> 3);
    const int s   = swz / (NQT_ * H_ * B_);
    int rem = swz - s * (NQT_ * H_ * B_);
    const int qt = rem % NQT_;
    const int bh = rem / NQT_;
    const int h = bh & 7, b = bh >> 3;
    const int q0 = qt * 128 + wv * 32;
    const int T0 = (s == 0) ? 0 : 9;
    const int T1 = (s == 0) ? 9 : NT;
    const size_t obase = (size_t)b * L_ * D_ + h * DH_;

    bf16x8 bqh[2][2];
#pragma unroll
    for (int g = 0; g < 2; ++g) {
        int gq = q0 + 16 * g + fr; if (gq > L_ - 1) gq = L_ - 1;
        const uint32_t* qrow = Qpk + (size_t)(b * L_ + gq) * D_ + h * DH_;
#pragma unroll
        for (int ss = 0; ss < 2; ++ss) {
            uint32_t r[8];
            *(u32x4*)&r[0] = *(const u32x4*)&qrow[ss * 32 + fq8];
            *(u32x4*)&r[4] = *(const u32x4*)&qrow[ss * 32 + fq8 + 4];
            bqh[g][ss] = unpk8h(r);
        }
    }

    float m[2] = {-1e30f, -1e30f};
    float lsum[2] = {0.f, 0.f};
    f32x4 oA[2][4];
#pragma unroll
    for (int g = 0; g < 2; ++g)
#pragma unroll
        for (int c = 0; c < 4; ++c) oA[g][c] = (f32x4){0.f, 0.f, 0.f, 0.f};

    const int sr = tid >> 2;
    const int sc = (tid & 3) * 16;
    const size_t kRowBase = (size_t)(b * L_) * D_ + h * DH_ + sc;
    const size_t vRowBase = ((size_t)bh * DH_ + sr) * LP_ + sc;

    u32x4 kR[4], vR[4];
    {
        int gr = T0 * 64 + sr; if (gr > L_ - 1) gr = L_ - 1;
        const uint32_t* kp = Kpk + kRowBase + (size_t)gr * D_;
        const uint32_t* vp = Vtpk + vRowBase + T0 * 64;
#pragma unroll
        for (int i = 0; i < 4; ++i) { kR[i] = *(const u32x4*)&kp[i * 4]; vR[i] = *(const u32x4*)&vp[i * 4]; }
#pragma unroll
        for (int i = 0; i < 4; ++i) {
            *(u32x4*)&Kls[sr][sc + i * 4] = kR[i];
            *(u32x4*)&Vls[sr][sc + i * 4] = vR[i];
        }
    }

    for (int t = T0; t < T1; ++t) {
        const int kt = t * 64;
        __syncthreads();

        if (t + 1 < T1) {
            int gr = kt + 64 + sr; if (gr > L_ - 1) gr = L_ - 1;
            const uint32_t* kp = Kpk + kRowBase + (size_t)gr * D_;
            const uint32_t* vp = Vtpk + vRowBase + (kt + 64);
#pragma unroll
            for (int i = 0; i < 4; ++i) { kR[i] = *(const u32x4*)&kp[i * 4]; vR[i] = *(const u32x4*)&vp[i * 4]; }
        }

        float p0[4][4], p1[4][4];
#pragma unroll
        for (int c = 0; c < 4; ++c) {
            const int row = 16 * c + fr;
            uint32_t r[8];
            *(u32x4*)&r[0] = *(u32x4*)&Kls[row][fq8];
            *(u32x4*)&r[4] = *(u32x4*)&Kls[row][fq8 + 4];
            bf16x8 ah0 = unpk8h(r);
            *(u32x4*)&r[0] = *(u32x4*)&Kls[row][32 + fq8];
            *(u32x4*)&r[4] = *(u32x4*)&Kls[row][32 + fq8 + 4];
            bf16x8 ah1 = unpk8h(r);
#pragma unroll
            for (int g = 0; g < 2; ++g) {
                f32x4 sacc = (f32x4){0.f, 0.f, 0.f, 0.f};
                sacc = __builtin_amdgcn_mfma_f32_16x16x32_bf16(ah0, bqh[g][0], sacc, 0, 0, 0);
                sacc = __builtin_amdgcn_mfma_f32_16x16x32_bf16(ah1, bqh[g][1], sacc, 0, 0, 0);
#pragma unroll
                for (int rr = 0; rr < 4; ++rr) {
                    int k = kt + 16 * c + 4 * fq + rr;
                    float val = (k < L_) ? sacc[rr] * SCALE_ : -1e30f;
                    if (g == 0) p0[c][rr] = val; else p1[c][rr] = val;
                }
            }
        }

        bf16x8 pah[2][2];
#pragma unroll
        for (int g = 0; g < 2; ++g) {
            float (*p)[4] = (g == 0) ? p0 : p1;
            float t0 = p[0][0];
#pragma unroll
            for (int c = 0; c < 4; ++c)
#pragma unroll
                for (int rr = 0; rr < 4; ++rr) t0 = fmaxf(t0, p[c][rr]);
            t0 = fmaxf(t0, __shfl_xor(t0, 16));
            t0 = fmaxf(t0, __shfl_xor(t0, 32));
            float mn = fmaxf(m[g], t0);
            float sclq = __expf(m[g] - mn);
            m[g] = mn;
            float ls = 0.f;
#pragma unroll
            for (int c = 0; c < 4; ++c)
#pragma unroll
                for (int rr = 0; rr < 4; ++rr) {
                    float e = __expf(p[c][rr] - mn);
                    p[c][rr] = e;
                    ls += e;
                }
            ls += __shfl_xor(ls, 16);
            ls += __shfl_xor(ls, 32);
            lsum[g] = lsum[g] * sclq + ls;
#pragma unroll
            for (int rr = 0; rr < 4; ++rr) {
                float sO = __shfl(sclq, 4 * fq + rr);
#pragma unroll
                for (int c2 = 0; c2 < 4; ++c2) oA[g][c2][rr] *= sO;
            }

            uint32_t pqh[4][2];
#pragma unroll
            for (int c = 0; c < 4; ++c) {
                pqh[c][0] = pk2f(p[c][0], p[c][1]);
                pqh[c][1] = pk2f(p[c][2], p[c][3]);
            }
            const int src0 = fr + ((fq & 1) << 5);
            const int src1 = src0 + 16;
            const bool sel = (fq >> 1) != 0;
#pragma unroll
            for (int ss = 0; ss < 2; ++ss) {
                const int c0 = 2 * ss, c1 = 2 * ss + 1;
                uint32_t A0 = (uint32_t)__shfl((int)pqh[c0][0], src0);
                uint32_t A1 = (uint32_t)__shfl((int)pqh[c0][1], src0);
                uint32_t A2 = (uint32_t)__shfl((int)pqh[c0][0], src1);
                uint32_t A3 = (uint32_t)__shfl((int)pqh[c0][1], src1);
                uint32_t B0 = (uint32_t)__shfl((int)pqh[c1][0], src0);
                uint32_t B1 = (uint32_t)__shfl((int)pqh[c1][1], src0);
                uint32_t B2 = (uint32_t)__shfl((int)pqh[c1][0], src1);
                uint32_t B3 = (uint32_t)__shfl((int)pqh[c1][1], src1);
                U4 uh;
                uh.u[0] = sel ? B0 : A0; uh.u[1] = sel ? B1 : A1;
                uh.u[2] = sel ? B2 : A2; uh.u[3] = sel ? B3 : A3;
                pah[g][ss] = uh.f;
            }
        }

        // ---- O += P_hi * V_hi (1-pass) ----
#pragma unroll
        for (int c2 = 0; c2 < 4; ++c2) {
            const int row = 16 * c2 + fr;
            uint32_t r[8];
            *(u32x4*)&r[0] = *(u32x4*)&Vls[row][fq8];
            *(u32x4*)&r[4] = *(u32x4*)&Vls[row][fq8 + 4];
            bf16x8 vh0 = unpk8h(r);
            *(u32x4*)&r[0] = *(u32x4*)&Vls[row][32 + fq8];
            *(u32x4*)&r[4] = *(u32x4*)&Vls[row][32 + fq8 + 4];
            bf16x8 vh1 = unpk8h(r);
#pragma unroll
            for (int g = 0; g < 2; ++g) {
                f32x4 o = oA[g][c2];
                o = __builtin_amdgcn_mfma_f32_16x16x32_bf16(pah[g][0], vh0, o, 0, 0, 0);
                o = __builtin_amdgcn_mfma_f32_16x16x32_bf16(pah[g][1], vh1, o, 0, 0, 0);
                oA[g][c2] = o;
            }
        }

        __syncthreads();
        if (t + 1 < T1) {
#pragma unroll
            for (int i = 0; i < 4; ++i) {
                *(u32x4*)&Kls[sr][sc + i * 4] = kR[i];
                *(u32x4*)&Vls[sr][sc + i * 4] = vR[i];
            }
        }
    }

    float* Op = Opart + (size_t)s * M_ * D_;
#pragma unroll
    for (int g = 0; g < 2; ++g) {
#pragma unroll
        for (int rr = 0; rr < 4; ++rr) {
            int row = q0 + 16 * g + 4 * fq + rr;
            if (row < L_) {
#pragma unroll
                for (int c2 = 0; c2 < 4; ++c2)
                    Op[obase + (size_t)row * D_ + 16 * c2 + fr] = oA[g][c2][rr];
            }
        }
        if (fq == 0) {
            int qrow = q0 + 16 * g + fr;
            if (qrow < L_) {
                size_t mlidx = (((size_t)s * B_ + b) * H_ + h) * L_ + qrow;
                ml[mlidx * 2]     = m[g];
                ml[mlidx * 2 + 1] = lsum[g];
            }
        }
    }
}

// ---------------- merge split-K partials -> bf16 (Wo GEMM A-operand) ----------------
__global__ __launch_bounds__(256) void attn_merge_kernel(
    const float* __restrict__ Opart, const float* __restrict__ ml,
    __bf16* __restrict__ Out) {
    int idx = blockIdx.x * 256 + threadIdx.x;
    if (idx >= M_ * 64) return;
    int row = idx >> 6;
    int seg = idx & 63;
    int col0 = seg * 8;
    int h = col0 >> 6;
    int b = row / L_;
    int l = row - b * L_;
    size_t i0 = ((((size_t)0 * B_ + b) * H_ + h) * L_ + l) * 2;
    size_t i1 = ((((size_t)1 * B_ + b) * H_ + h) * L_ + l) * 2;
    float m0 = ml[i0], l0 = ml[i0 + 1];
    float m1 = ml[i1], l1 = ml[i1 + 1];
    float mm = fmaxf(m0, m1);
    float e0 = __expf(m0 - mm), e1 = __expf(m1 - mm);
    float inv = 1.f / (e0 * l0 + e1 * l1);
    float w0 = e0 * inv, w1 = e1 * inv;
    size_t base = (size_t)row * D_ + col0;
    const float* O0 = Opart;
    const float* O1 = Opart + (size_t)M_ * D_;
    float4 a0 = *(const float4*)&O0[base];
    float4 a1 = *(const float4*)&O0[base + 4];
    float4 c0 = *(const float4*)&O1[base];
    float4 c1 = *(const float4*)&O1[base + 4];
    float o0 = w0 * a0.x + w1 * c0.x, o1v = w0 * a0.y + w1 * c0.y;
    float o2 = w0 * a0.z + w1 * c0.z, o3 = w0 * a0.w + w1 * c0.w;
    float o4 = w0 * a1.x + w1 * c1.x, o5 = w0 * a1.y + w1 * c1.y;
    float o6 = w0 * a1.z + w1 * c1.z, o7 = w0 * a1.w + w1 * c1.w;
    U4 u;
    u.u[0] = pk2f(o0, o1v); u.u[1] = pk2f(o2, o3);
    u.u[2] = pk2f(o4, o5);  u.u[3] = pk2f(o6, o7);
    *(u32x4*)&Out[base] = *(u32x4*)&u.u[0];
}

// ---------------- fused residual add + LayerNorm (+ optional bf16-hi out) ----------------
template <bool HIOUT>
__global__ __launch_bounds__(256) void add_ln_kernel(
    const float* __restrict__ X, const float* __restrict__ Y,
    const float* __restrict__ g, const float* __restrict__ be,
    float* __restrict__ Out, __bf16* __restrict__ Oh) {
    int wave = threadIdx.x >> 6;
    int lane = threadIdx.x & 63;
    int row = blockIdx.x * 4 + wave;
    if (row >= M_) return;
    size_t base = (size_t)row * D_;
    int c0 = lane * 4, c1 = 256 + lane * 4;
    float4 xa = *(const float4*)&X[base + c0];
    float4 xb = *(const float4*)&X[base + c1];
    float4 ya = *(const float4*)&Y[base + c0];
    float4 yb = *(const float4*)&Y[base + c1];
    float v[8] = {xa.x + ya.x, xa.y + ya.y, xa.z + ya.z, xa.w + ya.w,
                  xb.x + yb.x, xb.y + yb.y, xb.z + yb.z, xb.w + yb.w};
    float s = 0.f, s2 = 0.f;
#pragma unroll
    for (int i = 0; i < 8; ++i) { s += v[i]; s2 = fmaf(v[i], v[i], s2); }
#pragma unroll
    for (int off = 32; off > 0; off >>= 1) {
        s  += __shfl_xor(s, off);
        s2 += __shfl_xor(s2, off);
    }
    float mean = s * (1.f / D_);
    float var  = s2 * (1.f / D_) - mean * mean;
    float rstd = rsqrtf(var + EPS_);
    float4 ga = *(const float4*)&g[c0];
    float4 gb = *(const float4*)&g[c1];
    float4 ba = *(const float4*)&be[c0];
    float4 bb = *(const float4*)&be[c1];
    float o[8];
    o[0] = (v[0] - mean) * rstd * ga.x + ba.x;
    o[1] = (v[1] - mean) * rstd * ga.y + ba.y;
    o[2] = (v[2] - mean) * rstd * ga.z + ba.z;
    o[3] = (v[3] - mean) * rstd * ga.w + ba.w;
    o[4] = (v[4] - mean) * rstd * gb.x + bb.x;
    o[5] = (v[5] - mean) * rstd * gb.y + bb.y;
    o[6] = (v[6] - mean) * rstd * gb.z + bb.z;
    o[7] = (v[7] - mean) * rstd * gb.w + bb.w;
    *(float4*)&Out[base + c0] = make_float4(o[0], o[1], o[2], o[3]);
    *(float4*)&Out[base + c1] = make_float4(o[4], o[5], o[6], o[7]);
    if (HIOUT) {
        bf16x4 h0, h1;
#pragma unroll
        for (int i = 0; i < 4; ++i) {
            h0[i] = (__bf16)o[i];
            h1[i] = (__bf16)o[4 + i];
        }
        *(bf16x4*)&Oh[base + c0] = h0;
        *(bf16x4*)&Oh[base + c1] = h1;
    }
}

// ---------------- launch ----------------
extern "C" void kernel_launch(void* const* d_in, const int* in_sizes, int n_in,
                              void* d_out, int out_size, void* d_ws, size_t ws_size,
                              hipStream_t stream) {
    const float* embed1 = (const float*)d_in[0];
    const float* embed2 = (const float*)d_in[1];
    const float* cls    = (const float*)d_in[2];
    const float* Wq = (const float*)d_in[3];
    const float* bq = (const float*)d_in[4];
    const float* Wk = (const float*)d_in[5];
    const float* bk = (const float*)d_in[6];
    const float* Wv = (const float*)d_in[7];
    const float* bv = (const float*)d_in[8];
    const float* Wo = (const float*)d_in[9];
    const float* bo = (const float*)d_in[10];
    const float* ln1g = (const float*)d_in[11];
    const float* ln1b = (const float*)d_in[12];
    const float* W1 = (const float*)d_in[13];
    const float* b1 = (const float*)d_in[14];
    const float* W2 = (const float*)d_in[15];
    const float* b2 = (const float*)d_in[16];
    const float* ln2g = (const float*)d_in[17];
    const float* ln2b = (const float*)d_in[18];

    const size_t SZ = (size_t)M_ * D_;        // 4,198,400 floats
    float* ws = (float*)d_ws;
    float* X   = ws;                           // [0,SZ) fp32 residual stream
    __bf16* Xh = (__bf16*)(ws + SZ);           // [SZ,1.5SZ) bf16-hi of X
    __bf16* X2h = (__bf16*)(ws + SZ + SZ / 2); // [1.5SZ,2SZ) bf16-hi of X2
    float* Tb  = ws + 2 * SZ;                  // [2SZ,3SZ): fp32 scratch (X2 setup, FFN2 out)
    __bf16* Tbh = (__bf16*)(ws + 2 * SZ + SZ / 2); // merge out (attn phase; Tb fp32 dead then)
    uint32_t* Qpk = (uint32_t*)(ws + 3 * SZ);  // packed hi|lo
    float* WoOut  = (float*)Qpk;               // aliases Qpk (dead after attn)
    uint32_t* Kpk = (uint32_t*)(ws + 4 * SZ);
    uint32_t* Vtpk = (uint32_t*)(ws + 5 * SZ); // [5SZ,~6.07SZ) attn phase
    __bf16* Hbh = (__bf16*)(ws + 5 * SZ);      // [5SZ,7SZ) bf16 [M,DFF] FFN phase (aliases Vtpk)
    float* mlBuf   = ws + 6 * SZ + SZ / 2;     // stats (attn phase) -- inside Hbh region, dead by FFN
    float* Opart   = ws + 7 * SZ;              // [7SZ,9SZ) 2 partial O (attn phase)
    __bf16* wreg = (__bf16*)(ws + 9 * SZ);     // weight hi/lo planes

    const size_t NQl = (size_t)D_ * D_;                // 262144 per layer
    const size_t NQ  = (size_t)NLAYER_ * NQl;          // 524288
    const size_t NF  = (size_t)NLAYER_ * DFF_ * D_;    // 2097152
    __bf16* Wqh  = wreg;           __bf16* Wql  = Wqh + NQ;
    __bf16* Wkvh = Wql + NQ;       __bf16* Wkvl = Wkvh + 2 * NQ;  // [NLAYER][1024][512]
    __bf16* Woh  = Wkvl + 2 * NQ;  __bf16* Wol  = Woh + NQ;
    __bf16* W1h  = Wol + NQ;       __bf16* W1l  = W1h + NF;
    __bf16* W2h  = W1l + NF;       __bf16* W2l  = W2h + NF;

    split_w_kernel<<<(int)(NQ / 4 + 255) / 256, 256, 0, stream>>>(Wq, Wqh, Wql, (int)(NQ / 4));
    split_w_kernel<<<(int)(NQ / 4 + 255) / 256, 256, 0, stream>>>(Wo, Woh, Wol, (int)(NQ / 4));
    split_w_kernel<<<(int)(NF / 4 + 255) / 256, 256, 0, stream>>>(W1, W1h, W1l, (int)(NF / 4));
    split_w_kernel<<<(int)(NF / 4 + 255) / 256, 256, 0, stream>>>(W2, W2h, W2l, (int)(NF / 4));
    for (int l = 0; l < NLAYER_; ++l) {
        split_w_kernel<<<(int)(NQl / 4 + 255) / 256, 256, 0, stream>>>(
            Wk + l * NQl, Wkvh + l * 2 * NQl, Wkvl + l * 2 * NQl, (int)(NQl / 4));
        split_w_kernel<<<(int)(NQl / 4 + 255) / 256, 256, 0, stream>>>(
            Wv + l * NQl, Wkvh + l * 2 * NQl + NQl, Wkvl + l * 2 * NQl + NQl, (int)(NQl / 4));
    }

    // build X (fp32, persistent) and X2 (fp32 in Tb scratch, converted once)
    float* X2tmp = Tb;
    write_cls_kernel<<<(B_ * D_) / 256, 256, 0, stream>>>(cls, X, X2tmp);
    transpose_embed_kernel<<<dim3(L0_ / 32, D_ / 32, B_), dim3(32, 8), 0, stream>>>(embed1, X);
    transpose_embed_kernel<<<dim3(L0_ / 32, D_ / 32, B_), dim3(32, 8), 0, stream>>>(embed2, X2tmp);
    tobf16_kernel<<<(int)(SZ / 4 + 255) / 256, 256, 0, stream>>>(X, Xh, (int)(SZ / 4));
    tobf16_kernel<<<(int)(SZ / 4 + 255) / 256, 256, 0, stream>>>(X2tmp, X2h, (int)(SZ / 4));

    const int GM = (M_ + 127) / 128;         // 65
    const int g512  = GM * (512 / 64);       // 520
    const int g1024 = GM * (1024 / 64);      // 1040
    const int g2048 = GM * (2048 / 64);      // 2080
    const int gpad  = (B_ * H_ * DH_ * (LP_ - L_) + 255) / 256;
    const int gmerge = (M_ * 64 + 255) / 256;

    for (int l = 0; l < NLAYER_; ++l) {
        const size_t oQ = (size_t)l * NQl;
        const size_t oF = (size_t)l * DFF_ * D_;

        gemm_mfma_kernel<false, 1><<<g512, 256, 0, stream>>>(
            Xh, Wqh + oQ, Wql + oQ, bq + l * D_, nullptr, Qpk, nullptr, M_, D_, D_);
        gemm_kv_kernel<<<g1024, 256, 0, stream>>>(
            X2h, Wkvh + l * 2 * NQl, Wkvl + l * 2 * NQl,
            bk + l * D_, bv + l * D_, Kpk, Vtpk);
        zero_vt_pad_kernel<<<gpad, 256, 0, stream>>>(Vtpk);

        attn_mfma_kernel<<<NSPLIT_ * NQT_ * H_ * B_, 256, 0, stream>>>(
            Qpk, Kpk, Vtpk, Opart, mlBuf);
        attn_merge_kernel<<<gmerge, 256, 0, stream>>>(Opart, mlBuf, Tbh);

        gemm_mfma_kernel<false, 0><<<g512, 256, 0, stream>>>(
            Tbh, Woh + oQ, Wol + oQ, bo + l * D_, WoOut, nullptr, nullptr, M_, D_, D_);

        add_ln_kernel<true><<<(M_ + 3) / 4, 256, 0, stream>>>(
            X, WoOut, ln1g + l * D_, ln1b + l * D_, X, Xh);

        gemm_mfma_kernel<true, 2><<<g2048, 256, 0, stream>>>(
            Xh, W1h + oF, W1l + oF, b1 + l * DFF_, nullptr, nullptr, Hbh, M_, DFF_, D_);
        gemm_mfma_kernel<false, 0><<<g512, 256, 0, stream>>>(
            Hbh, W2h + oF, W2l + oF, b2 + l * D_, Tb, nullptr, nullptr, M_, D_, DFF_);

        if (l == NLAYER_ - 1) {
            add_ln_kernel<false><<<(M_ + 3) / 4, 256, 0, stream>>>(
                X, Tb, ln2g + l * D_, ln2b + l * D_, (float*)d_out, nullptr);
        } else {
            add_ln_kernel<true><<<(M_ + 3) / 4, 256, 0, stream>>>(
                X, Tb, ln2g + l * D_, ln2b + l * D_, X, Xh);
        }
    }
}

// Round 20
// 640.353 us; speedup vs baseline: 1.1478x; 1.0684x over previous
//
#include <hip/hip_runtime.h>
#include <hip/hip_bf16.h>

// ---------------- problem constants ----------------
constexpr int B_   = 8;
constexpr int D_   = 512;
constexpr int L0_  = 1024;
constexpr int L_   = 1025;          // L0 + cls
constexpr int H_   = 8;
constexpr int DH_  = 64;
constexpr int DFF_ = 2048;
constexpr int NLAYER_ = 2;
constexpr int M_   = B_ * L_;       // 8200 rows
constexpr int LP_  = 1088;          // padded L for Vt (17*64)
constexpr int NQT_ = 9;             // ceil(L/128) attn q-tiles
constexpr int NSPLIT_ = 2;          // K-range partitions (flash-decoding)
constexpr float EPS_   = 1e-6f;
constexpr float SCALE_ = 0.125f;    // 1/sqrt(64)

#define DEV_INLINE __device__ __forceinline__

typedef __attribute__((ext_vector_type(8))) __bf16 bf16x8;
typedef __attribute__((ext_vector_type(4))) __bf16 bf16x4;
typedef __attribute__((ext_vector_type(4))) float  f32x4;
typedef __attribute__((ext_vector_type(4))) unsigned int u32x4;

union U4 { uint32_t u[4]; bf16x8 f; };

DEV_INLINE float gelu_exact(float x) {
    return 0.5f * x * (1.f + erff(x * 0.70710678118654752f));
}

struct bfpair { __bf16 h, l; };
DEV_INLINE bfpair split_bf(float v) {
    bfpair p;
    p.h = (__bf16)v;
    p.l = (__bf16)(v - (float)p.h);
    return p;
}
DEV_INLINE uint16_t bfbits(float v) {
    __bf16 h = (__bf16)v;
    return __builtin_bit_cast(uint16_t, h);
}
DEV_INLINE uint32_t pk2f(float a, float b) {
    return (uint32_t)bfbits(a) | ((uint32_t)bfbits(b) << 16);
}

// ---------------- fp32 -> bf16 hi/lo plane split (weights) ----------------
__global__ __launch_bounds__(256) void split_w_kernel(
    const float* __restrict__ src, __bf16* __restrict__ hi,
    __bf16* __restrict__ lo, int n4) {
    int i = blockIdx.x * 256 + threadIdx.x;
    if (i >= n4) return;
    float4 v = *(const float4*)&src[i * 4];
    bf16x4 h, l;
    bfpair p0 = split_bf(v.x); h[0] = p0.h; l[0] = p0.l;
    bfpair p1 = split_bf(v.y); h[1] = p1.h; l[1] = p1.l;
    bfpair p2 = split_bf(v.z); h[2] = p2.h; l[2] = p2.l;
    bfpair p3 = split_bf(v.w); h[3] = p3.h; l[3] = p3.l;
    *(bf16x4*)&hi[i * 4] = h;
    *(bf16x4*)&lo[i * 4] = l;
}

// ---------------- fp32 -> bf16 (hi only) ----------------
__global__ __launch_bounds__(256) void tobf16_kernel(
    const float* __restrict__ src, __bf16* __restrict__ dst, int n4) {
    int i = blockIdx.x * 256 + threadIdx.x;
    if (i >= n4) return;
    float4 v = *(const float4*)&src[i * 4];
    bf16x4 h;
    h[0] = (__bf16)v.x; h[1] = (__bf16)v.y;
    h[2] = (__bf16)v.z; h[3] = (__bf16)v.w;
    *(bf16x4*)&dst[i * 4] = h;
}

// ---------------- zero Vt pad tokens (l = L_..LP_-1), bf16 ----------------
// CRITICAL: pad tokens feed PV MFMA with P=0; garbage bits can alias bf16
// Inf/NaN and 0*Inf = NaN (R10 failure). Must be zeroed every layer.
__global__ __launch_bounds__(256) void zero_vt_pad_kernel(__bf16* __restrict__ Vt) {
    constexpr int PAD = LP_ - L_;                 // 63
    int idx = blockIdx.x * 256 + threadIdx.x;
    int total = B_ * H_ * DH_ * PAD;
    if (idx >= total) return;
    int row = idx / PAD;
    int c   = idx - row * PAD;
    Vt[(size_t)row * LP_ + L_ + c] = (__bf16)0.f;
}

// ---------------- build x1/x2 ----------------
__global__ __launch_bounds__(256) void write_cls_kernel(
    const float* __restrict__ cls, float* __restrict__ X1, float* __restrict__ X2) {
    int idx = blockIdx.x * 256 + threadIdx.x;
    int b = idx >> 9;
    int d = idx & 511;
    float v = cls[d];
    X1[(size_t)b * L_ * D_ + d] = v;
    X2[(size_t)b * L_ * D_ + d] = v;
}

// embed [B, D, L0] -> X rows 1..L0
__global__ __launch_bounds__(256) void transpose_embed_kernel(
    const float* __restrict__ e, float* __restrict__ X) {
    __shared__ float tile[32][33];
    int b  = blockIdx.z;
    int i0 = blockIdx.x * 32;
    int d0 = blockIdx.y * 32;
    int tx = threadIdx.x;
    int ty = threadIdx.y;
#pragma unroll
    for (int j = 0; j < 32; j += 8)
        tile[ty + j][tx] = e[((size_t)b * D_ + d0 + ty + j) * L0_ + i0 + tx];
    __syncthreads();
#pragma unroll
    for (int j = 0; j < 32; j += 8)
        X[((size_t)b * L_ + 1 + i0 + ty + j) * D_ + d0 + tx] = tile[tx][ty + j];
}

// ---------------- 2-pass MFMA GEMM (bf16-hi A in global, W pre-split) ----------------
// R16 structure: reg-staging with next-tile prefetch (best measured).
// OUTMODE: 0 = fp32 C, 2 = bf16-hi Ch.
template <bool GELU, int OUTMODE>
__global__ __launch_bounds__(256) void gemm_mfma_kernel(
    const __bf16* __restrict__ A,
    const __bf16* __restrict__ Wh, const __bf16* __restrict__ Wl,
    const float* __restrict__ bias, float* __restrict__ C,
    __bf16* __restrict__ Ch, int M, int N, int K) {
    constexpr int BM = 128, BN = 64, BK = 32;
    constexpr int LDK = BK + 8;
    __shared__ alignas(16) __bf16 Ahs[BM][LDK];
    __shared__ alignas(16) __bf16 Bhs[BN][LDK];
    __shared__ alignas(16) __bf16 Bls[BN][LDK];

    const int GM = (M + BM - 1) / BM;
    const int nwg = gridDim.x;
    int bid = blockIdx.x;
    {
        int q = nwg >> 3, r = nwg & 7;
        int xcd = bid & 7, pos = bid >> 3;
        bid = (xcd < r) ? xcd * (q + 1) + pos
                        : r * (q + 1) + (xcd - r) * q + pos;
    }
    const int bn = bid / GM;
    const int bm = bid % GM;
    const int m0 = bm * BM;
    const int n0 = bn * BN;

    const int tid  = threadIdx.x;
    const int lane = tid & 63;
    const int wv   = tid >> 6;
    const int wr   = wv >> 1;
    const int wc   = wv & 1;
    const int fr   = lane & 15;
    const int fq   = lane >> 4;
    const int fq8  = fq * 8;
    const int mb   = wr * 64;
    const int nb   = wc * 32;

    const int srow = tid >> 2;          // 0..63
    const int scol = (tid & 3) * 8;     // bf16 col
    size_t aOff[2];
#pragma unroll
    for (int rep = 0; rep < 2; ++rep) {
        int r = m0 + srow + rep * 64;
        if (r > M - 1) r = M - 1;
        aOff[rep] = (size_t)r * K + scol;
    }
    const int swr = tid >> 2;
    const int swq = tid & 3;
    const size_t wOff = (size_t)(n0 + swr) * K + swq * 8;

    f32x4 acc[4][2];
#pragma unroll
    for (int i = 0; i < 4; ++i)
#pragma unroll
        for (int j = 0; j < 2; ++j) acc[i][j] = (f32x4){0.f, 0.f, 0.f, 0.f};

    const int nk = K / BK;
    u32x4 aR[2], wRh, wRl;
#pragma unroll
    for (int rep = 0; rep < 2; ++rep) aR[rep] = *(const u32x4*)&A[aOff[rep]];
    wRh = *(const u32x4*)&Wh[wOff];
    wRl = *(const u32x4*)&Wl[wOff];

    for (int kt = 0; kt < nk; ++kt) {
#pragma unroll
        for (int rep = 0; rep < 2; ++rep)
            *(u32x4*)&Ahs[srow + rep * 64][scol] = aR[rep];
        *(u32x4*)&Bhs[swr][swq * 8] = wRh;
        *(u32x4*)&Bls[swr][swq * 8] = wRl;
        __syncthreads();

        if (kt + 1 < nk) {
            int k0 = (kt + 1) * BK;
#pragma unroll
            for (int rep = 0; rep < 2; ++rep) aR[rep] = *(const u32x4*)&A[aOff[rep] + k0];
            wRh = *(const u32x4*)&Wh[wOff + k0];
            wRl = *(const u32x4*)&Wl[wOff + k0];
        }

        bf16x8 ah[4], bh[2], bl[2];
#pragma unroll
        for (int i = 0; i < 4; ++i)
            ah[i] = *(bf16x8*)&Ahs[mb + i * 16 + fr][fq8];
#pragma unroll
        for (int j = 0; j < 2; ++j) {
            bh[j] = *(bf16x8*)&Bhs[nb + j * 16 + fr][fq8];
            bl[j] = *(bf16x8*)&Bls[nb + j * 16 + fr][fq8];
        }
#pragma unroll
        for (int i = 0; i < 4; ++i)
#pragma unroll
            for (int j = 0; j < 2; ++j)
                acc[i][j] = __builtin_amdgcn_mfma_f32_16x16x32_bf16(ah[i], bh[j], acc[i][j], 0, 0, 0);
#pragma unroll
        for (int i = 0; i < 4; ++i)
#pragma unroll
            for (int j = 0; j < 2; ++j)
                acc[i][j] = __builtin_amdgcn_mfma_f32_16x16x32_bf16(ah[i], bl[j], acc[i][j], 0, 0, 0);
        __syncthreads();
    }

    const int ccol0 = n0 + nb + fr;
    const float b0 = bias[ccol0];
    const float b1 = bias[ccol0 + 16];
#pragma unroll
    for (int i = 0; i < 4; ++i) {
#pragma unroll
        for (int r = 0; r < 4; ++r) {
            int row = m0 + mb + i * 16 + fq * 4 + r;
            if (row < M) {
                float v0 = acc[i][0][r] + b0;
                float v1 = acc[i][1][r] + b1;
                if (GELU) { v0 = gelu_exact(v0); v1 = gelu_exact(v1); }
                if (OUTMODE == 2) {
                    Ch[(size_t)row * N + ccol0]      = (__bf16)v0;
                    Ch[(size_t)row * N + ccol0 + 16] = (__bf16)v1;
                } else {
                    C[(size_t)row * N + ccol0]      = v0;
                    C[(size_t)row * N + ccol0 + 16] = v1;
                }
            }
        }
    }
}

// ---------------- fused K+V GEMM, 2-pass, bf16 A -> bf16 K + transposed bf16 Vt ----------------
__global__ __launch_bounds__(256) void gemm_kv_kernel(
    const __bf16* __restrict__ A,
    const __bf16* __restrict__ Wh, const __bf16* __restrict__ Wl,
    const float* __restrict__ biasK, const float* __restrict__ biasV,
    __bf16* __restrict__ Kb, __bf16* __restrict__ Vt) {
    constexpr int BM = 128, BN = 64, BK = 32, K = 512;
    constexpr int LDK = BK + 8;
    __shared__ alignas(16) __bf16 Ahs[BM][LDK];
    __shared__ alignas(16) __bf16 Bhs[BN][LDK];
    __shared__ alignas(16) __bf16 Bls[BN][LDK];

    const int GM = (M_ + BM - 1) / BM;
    const int nwg = gridDim.x;
    int bid = blockIdx.x;
    {
        int q = nwg >> 3, r = nwg & 7;
        int xcd = bid & 7, pos = bid >> 3;
        bid = (xcd < r) ? xcd * (q + 1) + pos
                        : r * (q + 1) + (xcd - r) * q + pos;
    }
    const int bn = bid / GM;
    const int bm = bid % GM;
    const int m0 = bm * BM;
    const int n0 = bn * BN;

    const int tid  = threadIdx.x;
    const int lane = tid & 63;
    const int wv   = tid >> 6;
    const int wr   = wv >> 1;
    const int wc   = wv & 1;
    const int fr   = lane & 15;
    const int fq   = lane >> 4;
    const int fq8  = fq * 8;
    const int mb   = wr * 64;
    const int nb   = wc * 32;

    const int srow = tid >> 2;
    const int scol = (tid & 3) * 8;
    size_t aOff[2];
#pragma unroll
    for (int rep = 0; rep < 2; ++rep) {
        int r = m0 + srow + rep * 64;
        if (r > M_ - 1) r = M_ - 1;
        aOff[rep] = (size_t)r * K + scol;
    }
    const int swr = tid >> 2;
    const int swq = tid & 3;
    const size_t wOff = (size_t)(n0 + swr) * K + swq * 8;

    f32x4 acc[4][2];
#pragma unroll
    for (int i = 0; i < 4; ++i)
#pragma unroll
        for (int j = 0; j < 2; ++j) acc[i][j] = (f32x4){0.f, 0.f, 0.f, 0.f};

    const int nk = K / BK;
    u32x4 aR[2], wRh, wRl;
#pragma unroll
    for (int rep = 0; rep < 2; ++rep) aR[rep] = *(const u32x4*)&A[aOff[rep]];
    wRh = *(const u32x4*)&Wh[wOff];
    wRl = *(const u32x4*)&Wl[wOff];

    for (int kt = 0; kt < nk; ++kt) {
#pragma unroll
        for (int rep = 0; rep < 2; ++rep)
            *(u32x4*)&Ahs[srow + rep * 64][scol] = aR[rep];
        *(u32x4*)&Bhs[swr][swq * 8] = wRh;
        *(u32x4*)&Bls[swr][swq * 8] = wRl;
        __syncthreads();

        if (kt + 1 < nk) {
            int k0 = (kt + 1) * BK;
#pragma unroll
            for (int rep = 0; rep < 2; ++rep) aR[rep] = *(const u32x4*)&A[aOff[rep] + k0];
            wRh = *(const u32x4*)&Wh[wOff + k0];
            wRl = *(const u32x4*)&Wl[wOff + k0];
        }

        bf16x8 ah[4], bh[2], bl[2];
#pragma unroll
        for (int i = 0; i < 4; ++i)
            ah[i] = *(bf16x8*)&Ahs[mb + i * 16 + fr][fq8];
#pragma unroll
        for (int j = 0; j < 2; ++j) {
            bh[j] = *(bf16x8*)&Bhs[nb + j * 16 + fr][fq8];
            bl[j] = *(bf16x8*)&Bls[nb + j * 16 + fr][fq8];
        }
#pragma unroll
        for (int i = 0; i < 4; ++i)
#pragma unroll
            for (int j = 0; j < 2; ++j)
                acc[i][j] = __builtin_amdgcn_mfma_f32_16x16x32_bf16(ah[i], bh[j], acc[i][j], 0, 0, 0);
#pragma unroll
        for (int i = 0; i < 4; ++i)
#pragma unroll
            for (int j = 0; j < 2; ++j)
                acc[i][j] = __builtin_amdgcn_mfma_f32_16x16x32_bf16(ah[i], bl[j], acc[i][j], 0, 0, 0);
        __syncthreads();
    }

    const int ccol0 = n0 + nb + fr;
    if (n0 < 512) {
        const float b0 = biasK[ccol0];
        const float b1 = biasK[ccol0 + 16];
#pragma unroll
        for (int i = 0; i < 4; ++i) {
#pragma unroll
            for (int r = 0; r < 4; ++r) {
                int row = m0 + mb + i * 16 + fq * 4 + r;
                if (row < M_) {
                    Kb[(size_t)row * 512 + ccol0]      = (__bf16)(acc[i][0][r] + b0);
                    Kb[(size_t)row * 512 + ccol0 + 16] = (__bf16)(acc[i][1][r] + b1);
                }
            }
        }
    } else {
        const int cv = ccol0 - 512;
        const int h2 = cv >> 6, d2 = cv & 63;
        const float b0 = biasV[cv];
        const float b1 = biasV[cv + 16];
#pragma unroll
        for (int i = 0; i < 4; ++i) {
#pragma unroll
            for (int r = 0; r < 4; ++r) {
                int row = m0 + mb + i * 16 + fq * 4 + r;
                if (row < M_) {
                    int b2 = row / L_;
                    int l2 = row - b2 * L_;
                    size_t vb = (size_t)(b2 * H_ + h2) * DH_ * LP_;
                    Vt[vb + (size_t)d2 * LP_ + l2]        = (__bf16)(acc[i][0][r] + b0);
                    Vt[vb + (size_t)(d2 + 16) * LP_ + l2] = (__bf16)(acc[i][1][r] + b1);
                }
            }
        }
    }
}

// ---------------- MFMA flash attention, split-K, plain bf16 QKV ----------------
// QK^T: 1-pass bf16. PV: 1-pass. Zero unpack VALU: frags read directly from LDS.
__global__ __launch_bounds__(256) void attn_mfma_kernel(
    const __bf16* __restrict__ Qb, const __bf16* __restrict__ Kb,
    const __bf16* __restrict__ Vtb, float* __restrict__ Opart,
    float* __restrict__ ml) {
    constexpr int LDP = 72;                   // bf16 row stride (144B)
    constexpr int NT = (L_ + 63) / 64;        // 17
    __shared__ alignas(16) __bf16 Kls[64][LDP];
    __shared__ alignas(16) __bf16 Vls[64][LDP];

    const int tid  = threadIdx.x;
    const int lane = tid & 63;
    const int wv   = tid >> 6;
    const int fr   = lane & 15;
    const int fq   = lane >> 4;
    const int fq8  = fq * 8;

    int bid = blockIdx.x;
    int swz = (bid & 7) * (NSPLIT_ * NQT_ * H_ * B_ / 8) + (bid >> 3);
    const int s   = swz / (NQT_ * H_ * B_);
    int rem = swz - s * (NQT_ * H_ * B_);
    const int qt = rem % NQT_;
    const int bh = rem / NQT_;
    const int h = bh & 7, b = bh >> 3;
    const int q0 = qt * 128 + wv * 32;
    const int T0 = (s == 0) ? 0 : 9;
    const int T1 = (s == 0) ? 9 : NT;
    const size_t obase = (size_t)b * L_ * D_ + h * DH_;

    // Q fragments straight from global bf16
    bf16x8 bqh[2][2];
#pragma unroll
    for (int g = 0; g < 2; ++g) {
        int gq = q0 + 16 * g + fr; if (gq > L_ - 1) gq = L_ - 1;
        const __bf16* qrow = Qb + (size_t)(b * L_ + gq) * D_ + h * DH_;
#pragma unroll
        for (int ss = 0; ss < 2; ++ss)
            bqh[g][ss] = *(const bf16x8*)&qrow[ss * 32 + fq8];
    }

    float m[2] = {-1e30f, -1e30f};
    float lsum[2] = {0.f, 0.f};
    f32x4 oA[2][4];
#pragma unroll
    for (int g = 0; g < 2; ++g)
#pragma unroll
        for (int c = 0; c < 4; ++c) oA[g][c] = (f32x4){0.f, 0.f, 0.f, 0.f};

    // staging: row = tid>>2 (0..63), chunks at bf16 cols scb and scb+32
    const int sr  = tid >> 2;
    const int scb = (tid & 3) * 8;
    const size_t kRowBase = (size_t)(b * L_) * D_ + h * DH_ + scb;
    const size_t vRowBase = ((size_t)bh * DH_ + sr) * LP_ + scb;

    u32x4 kR[2], vR[2];
    {
        int gr = T0 * 64 + sr; if (gr > L_ - 1) gr = L_ - 1;
        const __bf16* kp = Kb + kRowBase + (size_t)gr * D_;
        const __bf16* vp = Vtb + vRowBase + T0 * 64;
        kR[0] = *(const u32x4*)&kp[0];  kR[1] = *(const u32x4*)&kp[32];
        vR[0] = *(const u32x4*)&vp[0];  vR[1] = *(const u32x4*)&vp[32];
        *(u32x4*)&Kls[sr][scb]      = kR[0];
        *(u32x4*)&Kls[sr][scb + 32] = kR[1];
        *(u32x4*)&Vls[sr][scb]      = vR[0];
        *(u32x4*)&Vls[sr][scb + 32] = vR[1];
    }

    for (int t = T0; t < T1; ++t) {
        const int kt = t * 64;
        __syncthreads();

        if (t + 1 < T1) {
            int gr = kt + 64 + sr; if (gr > L_ - 1) gr = L_ - 1;
            const __bf16* kp = Kb + kRowBase + (size_t)gr * D_;
            const __bf16* vp = Vtb + vRowBase + (kt + 64);
            kR[0] = *(const u32x4*)&kp[0];  kR[1] = *(const u32x4*)&kp[32];
            vR[0] = *(const u32x4*)&vp[0];  vR[1] = *(const u32x4*)&vp[32];
        }

        float p0[4][4], p1[4][4];
#pragma unroll
        for (int c = 0; c < 4; ++c) {
            const int row = 16 * c + fr;
            bf16x8 ah0 = *(bf16x8*)&Kls[row][fq8];
            bf16x8 ah1 = *(bf16x8*)&Kls[row][32 + fq8];
#pragma unroll
            for (int g = 0; g < 2; ++g) {
                f32x4 sacc = (f32x4){0.f, 0.f, 0.f, 0.f};
                sacc = __builtin_amdgcn_mfma_f32_16x16x32_bf16(ah0, bqh[g][0], sacc, 0, 0, 0);
                sacc = __builtin_amdgcn_mfma_f32_16x16x32_bf16(ah1, bqh[g][1], sacc, 0, 0, 0);
#pragma unroll
                for (int rr = 0; rr < 4; ++rr) {
                    int k = kt + 16 * c + 4 * fq + rr;
                    float val = (k < L_) ? sacc[rr] * SCALE_ : -1e30f;
                    if (g == 0) p0[c][rr] = val; else p1[c][rr] = val;
                }
            }
        }

        bf16x8 pah[2][2];
#pragma unroll
        for (int g = 0; g < 2; ++g) {
            float (*p)[4] = (g == 0) ? p0 : p1;
            float t0 = p[0][0];
#pragma unroll
            for (int c = 0; c < 4; ++c)
#pragma unroll
                for (int rr = 0; rr < 4; ++rr) t0 = fmaxf(t0, p[c][rr]);
            t0 = fmaxf(t0, __shfl_xor(t0, 16));
            t0 = fmaxf(t0, __shfl_xor(t0, 32));
            float mn = fmaxf(m[g], t0);
            float sclq = __expf(m[g] - mn);
            m[g] = mn;
            float ls = 0.f;
#pragma unroll
            for (int c = 0; c < 4; ++c)
#pragma unroll
                for (int rr = 0; rr < 4; ++rr) {
                    float e = __expf(p[c][rr] - mn);
                    p[c][rr] = e;
                    ls += e;
                }
            ls += __shfl_xor(ls, 16);
            ls += __shfl_xor(ls, 32);
            lsum[g] = lsum[g] * sclq + ls;
#pragma unroll
            for (int rr = 0; rr < 4; ++rr) {
                float sO = __shfl(sclq, 4 * fq + rr);
#pragma unroll
                for (int c2 = 0; c2 < 4; ++c2) oA[g][c2][rr] *= sO;
            }

            uint32_t pqh[4][2];
#pragma unroll
            for (int c = 0; c < 4; ++c) {
                pqh[c][0] = pk2f(p[c][0], p[c][1]);
                pqh[c][1] = pk2f(p[c][2], p[c][3]);
            }
            const int src0 = fr + ((fq & 1) << 5);
            const int src1 = src0 + 16;
            const bool sel = (fq >> 1) != 0;
#pragma unroll
            for (int ss = 0; ss < 2; ++ss) {
                const int c0 = 2 * ss, c1 = 2 * ss + 1;
                uint32_t A0 = (uint32_t)__shfl((int)pqh[c0][0], src0);
                uint32_t A1 = (uint32_t)__shfl((int)pqh[c0][1], src0);
                uint32_t A2 = (uint32_t)__shfl((int)pqh[c0][0], src1);
                uint32_t A3 = (uint32_t)__shfl((int)pqh[c0][1], src1);
                uint32_t B0 = (uint32_t)__shfl((int)pqh[c1][0], src0);
                uint32_t B1 = (uint32_t)__shfl((int)pqh[c1][1], src0);
                uint32_t B2 = (uint32_t)__shfl((int)pqh[c1][0], src1);
                uint32_t B3 = (uint32_t)__shfl((int)pqh[c1][1], src1);
                U4 uh;
                uh.u[0] = sel ? B0 : A0; uh.u[1] = sel ? B1 : A1;
                uh.u[2] = sel ? B2 : A2; uh.u[3] = sel ? B3 : A3;
                pah[g][ss] = uh.f;
            }
        }

        // ---- O += P_hi * V_hi (direct bf16 frag reads) ----
#pragma unroll
        for (int c2 = 0; c2 < 4; ++c2) {
            const int row = 16 * c2 + fr;
            bf16x8 vh0 = *(bf16x8*)&Vls[row][fq8];
            bf16x8 vh1 = *(bf16x8*)&Vls[row][32 + fq8];
#pragma unroll
            for (int g = 0; g < 2; ++g) {
                f32x4 o = oA[g][c2];
                o = __builtin_amdgcn_mfma_f32_16x16x32_bf16(pah[g][0], vh0, o, 0, 0, 0);
                o = __builtin_amdgcn_mfma_f32_16x16x32_bf16(pah[g][1], vh1, o, 0, 0, 0);
                oA[g][c2] = o;
            }
        }

        __syncthreads();
        if (t + 1 < T1) {
            *(u32x4*)&Kls[sr][scb]      = kR[0];
            *(u32x4*)&Kls[sr][scb + 32] = kR[1];
            *(u32x4*)&Vls[sr][scb]      = vR[0];
            *(u32x4*)&Vls[sr][scb + 32] = vR[1];
        }
    }

    float* Op = Opart + (size_t)s * M_ * D_;
#pragma unroll
    for (int g = 0; g < 2; ++g) {
#pragma unroll
        for (int rr = 0; rr < 4; ++rr) {
            int row = q0 + 16 * g + 4 * fq + rr;
            if (row < L_) {
#pragma unroll
                for (int c2 = 0; c2 < 4; ++c2)
                    Op[obase + (size_t)row * D_ + 16 * c2 + fr] = oA[g][c2][rr];
            }
        }
        if (fq == 0) {
            int qrow = q0 + 16 * g + fr;
            if (qrow < L_) {
                size_t mlidx = (((size_t)s * B_ + b) * H_ + h) * L_ + qrow;
                ml[mlidx * 2]     = m[g];
                ml[mlidx * 2 + 1] = lsum[g];
            }
        }
    }
}

// ---------------- merge split-K partials -> bf16 (Wo GEMM A-operand) ----------------
__global__ __launch_bounds__(256) void attn_merge_kernel(
    const float* __restrict__ Opart, const float* __restrict__ ml,
    __bf16* __restrict__ Out) {
    int idx = blockIdx.x * 256 + threadIdx.x;
    if (idx >= M_ * 64) return;
    int row = idx >> 6;
    int seg = idx & 63;
    int col0 = seg * 8;
    int h = col0 >> 6;
    int b = row / L_;
    int l = row - b * L_;
    size_t i0 = ((((size_t)0 * B_ + b) * H_ + h) * L_ + l) * 2;
    size_t i1 = ((((size_t)1 * B_ + b) * H_ + h) * L_ + l) * 2;
    float m0 = ml[i0], l0 = ml[i0 + 1];
    float m1 = ml[i1], l1 = ml[i1 + 1];
    float mm = fmaxf(m0, m1);
    float e0 = __expf(m0 - mm), e1 = __expf(m1 - mm);
    float inv = 1.f / (e0 * l0 + e1 * l1);
    float w0 = e0 * inv, w1 = e1 * inv;
    size_t base = (size_t)row * D_ + col0;
    const float* O0 = Opart;
    const float* O1 = Opart + (size_t)M_ * D_;
    float4 a0 = *(const float4*)&O0[base];
    float4 a1 = *(const float4*)&O0[base + 4];
    float4 c0 = *(const float4*)&O1[base];
    float4 c1 = *(const float4*)&O1[base + 4];
    float o0 = w0 * a0.x + w1 * c0.x, o1v = w0 * a0.y + w1 * c0.y;
    float o2 = w0 * a0.z + w1 * c0.z, o3 = w0 * a0.w + w1 * c0.w;
    float o4 = w0 * a1.x + w1 * c1.x, o5 = w0 * a1.y + w1 * c1.y;
    float o6 = w0 * a1.z + w1 * c1.z, o7 = w0 * a1.w + w1 * c1.w;
    U4 u;
    u.u[0] = pk2f(o0, o1v); u.u[1] = pk2f(o2, o3);
    u.u[2] = pk2f(o4, o5);  u.u[3] = pk2f(o6, o7);
    *(u32x4*)&Out[base] = *(u32x4*)&u.u[0];
}

// ---------------- fused residual add + LayerNorm (+ optional bf16-hi out) ----------------
template <bool HIOUT>
__global__ __launch_bounds__(256) void add_ln_kernel(
    const float* __restrict__ X, const float* __restrict__ Y,
    const float* __restrict__ g, const float* __restrict__ be,
    float* __restrict__ Out, __bf16* __restrict__ Oh) {
    int wave = threadIdx.x >> 6;
    int lane = threadIdx.x & 63;
    int row = blockIdx.x * 4 + wave;
    if (row >= M_) return;
    size_t base = (size_t)row * D_;
    int c0 = lane * 4, c1 = 256 + lane * 4;
    float4 xa = *(const float4*)&X[base + c0];
    float4 xb = *(const float4*)&X[base + c1];
    float4 ya = *(const float4*)&Y[base + c0];
    float4 yb = *(const float4*)&Y[base + c1];
    float v[8] = {xa.x + ya.x, xa.y + ya.y, xa.z + ya.z, xa.w + ya.w,
                  xb.x + yb.x, xb.y + yb.y, xb.z + yb.z, xb.w + yb.w};
    float s = 0.f, s2 = 0.f;
#pragma unroll
    for (int i = 0; i < 8; ++i) { s += v[i]; s2 = fmaf(v[i], v[i], s2); }
#pragma unroll
    for (int off = 32; off > 0; off >>= 1) {
        s  += __shfl_xor(s, off);
        s2 += __shfl_xor(s2, off);
    }
    float mean = s * (1.f / D_);
    float var  = s2 * (1.f / D_) - mean * mean;
    float rstd = rsqrtf(var + EPS_);
    float4 ga = *(const float4*)&g[c0];
    float4 gb = *(const float4*)&g[c1];
    float4 ba = *(const float4*)&be[c0];
    float4 bb = *(const float4*)&be[c1];
    float o[8];
    o[0] = (v[0] - mean) * rstd * ga.x + ba.x;
    o[1] = (v[1] - mean) * rstd * ga.y + ba.y;
    o[2] = (v[2] - mean) * rstd * ga.z + ba.z;
    o[3] = (v[3] - mean) * rstd * ga.w + ba.w;
    o[4] = (v[4] - mean) * rstd * gb.x + bb.x;
    o[5] = (v[5] - mean) * rstd * gb.y + bb.y;
    o[6] = (v[6] - mean) * rstd * gb.z + bb.z;
    o[7] = (v[7] - mean) * rstd * gb.w + bb.w;
    *(float4*)&Out[base + c0] = make_float4(o[0], o[1], o[2], o[3]);
    *(float4*)&Out[base + c1] = make_float4(o[4], o[5], o[6], o[7]);
    if (HIOUT) {
        bf16x4 h0, h1;
#pragma unroll
        for (int i = 0; i < 4; ++i) {
            h0[i] = (__bf16)o[i];
            h1[i] = (__bf16)o[4 + i];
        }
        *(bf16x4*)&Oh[base + c0] = h0;
        *(bf16x4*)&Oh[base + c1] = h1;
    }
}

// ---------------- launch ----------------
extern "C" void kernel_launch(void* const* d_in, const int* in_sizes, int n_in,
                              void* d_out, int out_size, void* d_ws, size_t ws_size,
                              hipStream_t stream) {
    const float* embed1 = (const float*)d_in[0];
    const float* embed2 = (const float*)d_in[1];
    const float* cls    = (const float*)d_in[2];
    const float* Wq = (const float*)d_in[3];
    const float* bq = (const float*)d_in[4];
    const float* Wk = (const float*)d_in[5];
    const float* bk = (const float*)d_in[6];
    const float* Wv = (const float*)d_in[7];
    const float* bv = (const float*)d_in[8];
    const float* Wo = (const float*)d_in[9];
    const float* bo = (const float*)d_in[10];
    const float* ln1g = (const float*)d_in[11];
    const float* ln1b = (const float*)d_in[12];
    const float* W1 = (const float*)d_in[13];
    const float* b1 = (const float*)d_in[14];
    const float* W2 = (const float*)d_in[15];
    const float* b2 = (const float*)d_in[16];
    const float* ln2g = (const float*)d_in[17];
    const float* ln2b = (const float*)d_in[18];

    const size_t SZ = (size_t)M_ * D_;        // 4,198,400 floats
    float* ws = (float*)d_ws;
    float* X   = ws;                           // [0,SZ) fp32 residual stream
    __bf16* Xh = (__bf16*)(ws + SZ);           // [SZ,1.5SZ) bf16-hi of X
    __bf16* X2h = (__bf16*)(ws + SZ + SZ / 2); // [1.5SZ,2SZ) bf16-hi of X2
    float* Tb  = ws + 2 * SZ;                  // [2SZ,3SZ): fp32 scratch (X2 setup, FFN2 out)
    __bf16* Tbh = (__bf16*)(ws + 2 * SZ + SZ / 2); // merge out (attn phase; Tb fp32 dead then)
    __bf16* Qbh = (__bf16*)(ws + 3 * SZ);      // [3SZ,3.5SZ) bf16 Q (attn phase)
    float* WoOut  = (float*)(ws + 3 * SZ);     // aliases Qbh region (dead after attn)
    __bf16* Kbh = (__bf16*)(ws + 4 * SZ);      // [4SZ,4.5SZ) bf16 K
    __bf16* Vtb = (__bf16*)(ws + 5 * SZ);      // [5SZ,~5.54SZ) bf16 Vt (attn phase)
    __bf16* Hbh = (__bf16*)(ws + 5 * SZ);      // [5SZ,7SZ) bf16 [M,DFF] FFN phase (aliases Vtb)
    float* mlBuf   = ws + 6 * SZ + SZ / 2;     // stats (attn phase) -- past Vt end, dead by FFN
    float* Opart   = ws + 7 * SZ;              // [7SZ,9SZ) 2 partial O (attn phase)
    __bf16* wreg = (__bf16*)(ws + 9 * SZ);     // weight hi/lo planes

    const size_t NQl = (size_t)D_ * D_;                // 262144 per layer
    const size_t NQ  = (size_t)NLAYER_ * NQl;          // 524288
    const size_t NF  = (size_t)NLAYER_ * DFF_ * D_;    // 2097152
    __bf16* Wqh  = wreg;           __bf16* Wql  = Wqh + NQ;
    __bf16* Wkvh = Wql + NQ;       __bf16* Wkvl = Wkvh + 2 * NQ;  // [NLAYER][1024][512]
    __bf16* Woh  = Wkvl + 2 * NQ;  __bf16* Wol  = Woh + NQ;
    __bf16* W1h  = Wol + NQ;       __bf16* W1l  = W1h + NF;
    __bf16* W2h  = W1l + NF;       __bf16* W2l  = W2h + NF;

    split_w_kernel<<<(int)(NQ / 4 + 255) / 256, 256, 0, stream>>>(Wq, Wqh, Wql, (int)(NQ / 4));
    split_w_kernel<<<(int)(NQ / 4 + 255) / 256, 256, 0, stream>>>(Wo, Woh, Wol, (int)(NQ / 4));
    split_w_kernel<<<(int)(NF / 4 + 255) / 256, 256, 0, stream>>>(W1, W1h, W1l, (int)(NF / 4));
    split_w_kernel<<<(int)(NF / 4 + 255) / 256, 256, 0, stream>>>(W2, W2h, W2l, (int)(NF / 4));
    for (int l = 0; l < NLAYER_; ++l) {
        split_w_kernel<<<(int)(NQl / 4 + 255) / 256, 256, 0, stream>>>(
            Wk + l * NQl, Wkvh + l * 2 * NQl, Wkvl + l * 2 * NQl, (int)(NQl / 4));
        split_w_kernel<<<(int)(NQl / 4 + 255) / 256, 256, 0, stream>>>(
            Wv + l * NQl, Wkvh + l * 2 * NQl + NQl, Wkvl + l * 2 * NQl + NQl, (int)(NQl / 4));
    }

    // build X (fp32, persistent) and X2 (fp32 in Tb scratch, converted once)
    float* X2tmp = Tb;
    write_cls_kernel<<<(B_ * D_) / 256, 256, 0, stream>>>(cls, X, X2tmp);
    transpose_embed_kernel<<<dim3(L0_ / 32, D_ / 32, B_), dim3(32, 8), 0, stream>>>(embed1, X);
    transpose_embed_kernel<<<dim3(L0_ / 32, D_ / 32, B_), dim3(32, 8), 0, stream>>>(embed2, X2tmp);
    tobf16_kernel<<<(int)(SZ / 4 + 255) / 256, 256, 0, stream>>>(X, Xh, (int)(SZ / 4));
    tobf16_kernel<<<(int)(SZ / 4 + 255) / 256, 256, 0, stream>>>(X2tmp, X2h, (int)(SZ / 4));

    const int GM = (M_ + 127) / 128;         // 65
    const int g512  = GM * (512 / 64);       // 520
    const int g1024 = GM * (1024 / 64);      // 1040
    const int g2048 = GM * (2048 / 64);      // 2080
    const int gpad  = (B_ * H_ * DH_ * (LP_ - L_) + 255) / 256;
    const int gmerge = (M_ * 64 + 255) / 256;

    for (int l = 0; l < NLAYER_; ++l) {
        const size_t oQ = (size_t)l * NQl;
        const size_t oF = (size_t)l * DFF_ * D_;

        gemm_mfma_kernel<false, 2><<<g512, 256, 0, stream>>>(
            Xh, Wqh + oQ, Wql + oQ, bq + l * D_, nullptr, Qbh, M_, D_, D_);
        gemm_kv_kernel<<<g1024, 256, 0, stream>>>(
            X2h, Wkvh + l * 2 * NQl, Wkvl + l * 2 * NQl,
            bk + l * D_, bv + l * D_, Kbh, Vtb);
        zero_vt_pad_kernel<<<gpad, 256, 0, stream>>>(Vtb);

        attn_mfma_kernel<<<NSPLIT_ * NQT_ * H_ * B_, 256, 0, stream>>>(
            Qbh, Kbh, Vtb, Opart, mlBuf);
        attn_merge_kernel<<<gmerge, 256, 0, stream>>>(Opart, mlBuf, Tbh);

        gemm_mfma_kernel<false, 0><<<g512, 256, 0, stream>>>(
            Tbh, Woh + oQ, Wol + oQ, bo + l * D_, WoOut, nullptr, M_, D_, D_);

        add_ln_kernel<true><<<(M_ + 3) / 4, 256, 0, stream>>>(
            X, WoOut, ln1g + l * D_, ln1b + l * D_, X, Xh);

        gemm_mfma_kernel<true, 2><<<g2048, 256, 0, stream>>>(
            Xh, W1h + oF, W1l + oF, b1 + l * DFF_, nullptr, Hbh, M_, DFF_, D_);
        gemm_mfma_kernel<false, 0><<<g512, 256, 0, stream>>>(
            Hbh, W2h + oF, W2l + oF, b2 + l * D_, Tb, nullptr, M_, D_, DFF_);

        if (l == NLAYER_ - 1) {
            add_ln_kernel<false><<<(M_ + 3) / 4, 256, 0, stream>>>(
                X, Tb, ln2g + l * D_, ln2b + l * D_, (float*)d_out, nullptr);
        } else {
            add_ln_kernel<true><<<(M_ + 3) / 4, 256, 0, stream>>>(
                X, Tb, ln2g + l * D_, ln2b + l * D_, X, Xh);
        }
    }
}

// Round 21
// 577.740 us; speedup vs baseline: 1.2722x; 1.1084x over previous
//
#include <hip/hip_runtime.h>
#include <hip/hip_bf16.h>

// ---------------- problem constants ----------------
constexpr int B_   = 8;
constexpr int D_   = 512;
constexpr int L0_  = 1024;
constexpr int L_   = 1025;          // L0 + cls
constexpr int H_   = 8;
constexpr int DH_  = 64;
constexpr int DFF_ = 2048;
constexpr int NLAYER_ = 2;
constexpr int M_   = B_ * L_;       // 8200 rows
constexpr int LP_  = 1088;          // padded L for Vt (17*64)
constexpr int NQT_ = 9;             // ceil(L/128) attn q-tiles
constexpr int NSPLIT_ = 2;          // K-range partitions (flash-decoding)
constexpr float EPS_   = 1e-6f;
constexpr float SCALE_ = 0.125f;    // 1/sqrt(64)

#define DEV_INLINE __device__ __forceinline__

typedef __attribute__((ext_vector_type(8))) __bf16 bf16x8;
typedef __attribute__((ext_vector_type(4))) __bf16 bf16x4;
typedef __attribute__((ext_vector_type(4))) float  f32x4;
typedef __attribute__((ext_vector_type(4))) unsigned int u32x4;

union U4 { uint32_t u[4]; bf16x8 f; };

DEV_INLINE float gelu_exact(float x) {
    return 0.5f * x * (1.f + erff(x * 0.70710678118654752f));
}

DEV_INLINE uint16_t bfbits(float v) {
    __bf16 h = (__bf16)v;
    return __builtin_bit_cast(uint16_t, h);
}
DEV_INLINE uint32_t pk2f(float a, float b) {
    return (uint32_t)bfbits(a) | ((uint32_t)bfbits(b) << 16);
}

// ---------------- fp32 -> bf16 ----------------
__global__ __launch_bounds__(256) void tobf16_kernel(
    const float* __restrict__ src, __bf16* __restrict__ dst, int n4) {
    int i = blockIdx.x * 256 + threadIdx.x;
    if (i >= n4) return;
    float4 v = *(const float4*)&src[i * 4];
    bf16x4 h;
    h[0] = (__bf16)v.x; h[1] = (__bf16)v.y;
    h[2] = (__bf16)v.z; h[3] = (__bf16)v.w;
    *(bf16x4*)&dst[i * 4] = h;
}

// ---------------- zero Vt pad tokens (l = L_..LP_-1), bf16 ----------------
// CRITICAL: pad tokens feed PV MFMA with P=0; garbage bits can alias bf16
// Inf/NaN and 0*Inf = NaN (R10 failure). Must be zeroed every layer.
__global__ __launch_bounds__(256) void zero_vt_pad_kernel(__bf16* __restrict__ Vt) {
    constexpr int PAD = LP_ - L_;                 // 63
    int idx = blockIdx.x * 256 + threadIdx.x;
    int total = B_ * H_ * DH_ * PAD;
    if (idx >= total) return;
    int row = idx / PAD;
    int c   = idx - row * PAD;
    Vt[(size_t)row * LP_ + L_ + c] = (__bf16)0.f;
}

// ---------------- build x1/x2 ----------------
__global__ __launch_bounds__(256) void write_cls_kernel(
    const float* __restrict__ cls, float* __restrict__ X1, float* __restrict__ X2) {
    int idx = blockIdx.x * 256 + threadIdx.x;
    int b = idx >> 9;
    int d = idx & 511;
    float v = cls[d];
    X1[(size_t)b * L_ * D_ + d] = v;
    X2[(size_t)b * L_ * D_ + d] = v;
}

// embed [B, D, L0] -> X rows 1..L0
__global__ __launch_bounds__(256) void transpose_embed_kernel(
    const float* __restrict__ e, float* __restrict__ X) {
    __shared__ float tile[32][33];
    int b  = blockIdx.z;
    int i0 = blockIdx.x * 32;
    int d0 = blockIdx.y * 32;
    int tx = threadIdx.x;
    int ty = threadIdx.y;
#pragma unroll
    for (int j = 0; j < 32; j += 8)
        tile[ty + j][tx] = e[((size_t)b * D_ + d0 + ty + j) * L0_ + i0 + tx];
    __syncthreads();
#pragma unroll
    for (int j = 0; j < 32; j += 8)
        X[((size_t)b * L_ + 1 + i0 + ty + j) * D_ + d0 + tx] = tile[tx][ty + j];
}

// ---------------- pure bf16 MFMA GEMM (1-pass) ----------------
// C = A*W^T + bias; A and W both plain bf16 in global.
// R16 staging structure: reg prefetch of next tile. OUTMODE: 0 = fp32, 2 = bf16.
template <bool GELU, int OUTMODE>
__global__ __launch_bounds__(256) void gemm_mfma_kernel(
    const __bf16* __restrict__ A, const __bf16* __restrict__ Wh,
    const float* __restrict__ bias, float* __restrict__ C,
    __bf16* __restrict__ Ch, int M, int N, int K) {
    constexpr int BM = 128, BN = 64, BK = 32;
    constexpr int LDK = BK + 8;
    __shared__ alignas(16) __bf16 Ahs[BM][LDK];
    __shared__ alignas(16) __bf16 Bhs[BN][LDK];

    const int GM = (M + BM - 1) / BM;
    const int nwg = gridDim.x;
    int bid = blockIdx.x;
    {
        int q = nwg >> 3, r = nwg & 7;
        int xcd = bid & 7, pos = bid >> 3;
        bid = (xcd < r) ? xcd * (q + 1) + pos
                        : r * (q + 1) + (xcd - r) * q + pos;
    }
    const int bn = bid / GM;
    const int bm = bid % GM;
    const int m0 = bm * BM;
    const int n0 = bn * BN;

    const int tid  = threadIdx.x;
    const int lane = tid & 63;
    const int wv   = tid >> 6;
    const int wr   = wv >> 1;
    const int wc   = wv & 1;
    const int fr   = lane & 15;
    const int fq   = lane >> 4;
    const int fq8  = fq * 8;
    const int mb   = wr * 64;
    const int nb   = wc * 32;

    const int srow = tid >> 2;          // 0..63
    const int scol = (tid & 3) * 8;     // bf16 col
    size_t aOff[2];
#pragma unroll
    for (int rep = 0; rep < 2; ++rep) {
        int r = m0 + srow + rep * 64;
        if (r > M - 1) r = M - 1;
        aOff[rep] = (size_t)r * K + scol;
    }
    const size_t wOff = (size_t)(n0 + srow) * K + scol;

    f32x4 acc[4][2];
#pragma unroll
    for (int i = 0; i < 4; ++i)
#pragma unroll
        for (int j = 0; j < 2; ++j) acc[i][j] = (f32x4){0.f, 0.f, 0.f, 0.f};

    const int nk = K / BK;
    u32x4 aR[2], wRh;
#pragma unroll
    for (int rep = 0; rep < 2; ++rep) aR[rep] = *(const u32x4*)&A[aOff[rep]];
    wRh = *(const u32x4*)&Wh[wOff];

    for (int kt = 0; kt < nk; ++kt) {
#pragma unroll
        for (int rep = 0; rep < 2; ++rep)
            *(u32x4*)&Ahs[srow + rep * 64][scol] = aR[rep];
        *(u32x4*)&Bhs[srow][scol] = wRh;
        __syncthreads();

        if (kt + 1 < nk) {
            int k0 = (kt + 1) * BK;
#pragma unroll
            for (int rep = 0; rep < 2; ++rep) aR[rep] = *(const u32x4*)&A[aOff[rep] + k0];
            wRh = *(const u32x4*)&Wh[wOff + k0];
        }

        bf16x8 ah[4], bh[2];
#pragma unroll
        for (int i = 0; i < 4; ++i)
            ah[i] = *(bf16x8*)&Ahs[mb + i * 16 + fr][fq8];
#pragma unroll
        for (int j = 0; j < 2; ++j)
            bh[j] = *(bf16x8*)&Bhs[nb + j * 16 + fr][fq8];
#pragma unroll
        for (int i = 0; i < 4; ++i)
#pragma unroll
            for (int j = 0; j < 2; ++j)
                acc[i][j] = __builtin_amdgcn_mfma_f32_16x16x32_bf16(ah[i], bh[j], acc[i][j], 0, 0, 0);
        __syncthreads();
    }

    const int ccol0 = n0 + nb + fr;
    const float b0 = bias[ccol0];
    const float b1 = bias[ccol0 + 16];
#pragma unroll
    for (int i = 0; i < 4; ++i) {
#pragma unroll
        for (int r = 0; r < 4; ++r) {
            int row = m0 + mb + i * 16 + fq * 4 + r;
            if (row < M) {
                float v0 = acc[i][0][r] + b0;
                float v1 = acc[i][1][r] + b1;
                if (GELU) { v0 = gelu_exact(v0); v1 = gelu_exact(v1); }
                if (OUTMODE == 2) {
                    Ch[(size_t)row * N + ccol0]      = (__bf16)v0;
                    Ch[(size_t)row * N + ccol0 + 16] = (__bf16)v1;
                } else {
                    C[(size_t)row * N + ccol0]      = v0;
                    C[(size_t)row * N + ccol0 + 16] = v1;
                }
            }
        }
    }
}

// ---------------- fused K+V GEMM, 1-pass bf16 (V stored transposed) ----------------
__global__ __launch_bounds__(256) void gemm_kv_kernel(
    const __bf16* __restrict__ A, const __bf16* __restrict__ Wh,
    const float* __restrict__ biasK, const float* __restrict__ biasV,
    __bf16* __restrict__ Kb, __bf16* __restrict__ Vt) {
    constexpr int BM = 128, BN = 64, BK = 32, K = 512;
    constexpr int LDK = BK + 8;
    __shared__ alignas(16) __bf16 Ahs[BM][LDK];
    __shared__ alignas(16) __bf16 Bhs[BN][LDK];

    const int GM = (M_ + BM - 1) / BM;
    const int nwg = gridDim.x;
    int bid = blockIdx.x;
    {
        int q = nwg >> 3, r = nwg & 7;
        int xcd = bid & 7, pos = bid >> 3;
        bid = (xcd < r) ? xcd * (q + 1) + pos
                        : r * (q + 1) + (xcd - r) * q + pos;
    }
    const int bn = bid / GM;
    const int bm = bid % GM;
    const int m0 = bm * BM;
    const int n0 = bn * BN;

    const int tid  = threadIdx.x;
    const int lane = tid & 63;
    const int wv   = tid >> 6;
    const int wr   = wv >> 1;
    const int wc   = wv & 1;
    const int fr   = lane & 15;
    const int fq   = lane >> 4;
    const int fq8  = fq * 8;
    const int mb   = wr * 64;
    const int nb   = wc * 32;

    const int srow = tid >> 2;
    const int scol = (tid & 3) * 8;
    size_t aOff[2];
#pragma unroll
    for (int rep = 0; rep < 2; ++rep) {
        int r = m0 + srow + rep * 64;
        if (r > M_ - 1) r = M_ - 1;
        aOff[rep] = (size_t)r * K + scol;
    }
    const size_t wOff = (size_t)(n0 + srow) * K + scol;

    f32x4 acc[4][2];
#pragma unroll
    for (int i = 0; i < 4; ++i)
#pragma unroll
        for (int j = 0; j < 2; ++j) acc[i][j] = (f32x4){0.f, 0.f, 0.f, 0.f};

    const int nk = K / BK;
    u32x4 aR[2], wRh;
#pragma unroll
    for (int rep = 0; rep < 2; ++rep) aR[rep] = *(const u32x4*)&A[aOff[rep]];
    wRh = *(const u32x4*)&Wh[wOff];

    for (int kt = 0; kt < nk; ++kt) {
#pragma unroll
        for (int rep = 0; rep < 2; ++rep)
            *(u32x4*)&Ahs[srow + rep * 64][scol] = aR[rep];
        *(u32x4*)&Bhs[srow][scol] = wRh;
        __syncthreads();

        if (kt + 1 < nk) {
            int k0 = (kt + 1) * BK;
#pragma unroll
            for (int rep = 0; rep < 2; ++rep) aR[rep] = *(const u32x4*)&A[aOff[rep] + k0];
            wRh = *(const u32x4*)&Wh[wOff + k0];
        }

        bf16x8 ah[4], bh[2];
#pragma unroll
        for (int i = 0; i < 4; ++i)
            ah[i] = *(bf16x8*)&Ahs[mb + i * 16 + fr][fq8];
#pragma unroll
        for (int j = 0; j < 2; ++j)
            bh[j] = *(bf16x8*)&Bhs[nb + j * 16 + fr][fq8];
#pragma unroll
        for (int i = 0; i < 4; ++i)
#pragma unroll
            for (int j = 0; j < 2; ++j)
                acc[i][j] = __builtin_amdgcn_mfma_f32_16x16x32_bf16(ah[i], bh[j], acc[i][j], 0, 0, 0);
        __syncthreads();
    }

    const int ccol0 = n0 + nb + fr;
    if (n0 < 512) {
        const float b0 = biasK[ccol0];
        const float b1 = biasK[ccol0 + 16];
#pragma unroll
        for (int i = 0; i < 4; ++i) {
#pragma unroll
            for (int r = 0; r < 4; ++r) {
                int row = m0 + mb + i * 16 + fq * 4 + r;
                if (row < M_) {
                    Kb[(size_t)row * 512 + ccol0]      = (__bf16)(acc[i][0][r] + b0);
                    Kb[(size_t)row * 512 + ccol0 + 16] = (__bf16)(acc[i][1][r] + b1);
                }
            }
        }
    } else {
        const int cv = ccol0 - 512;
        const int h2 = cv >> 6, d2 = cv & 63;
        const float b0 = biasV[cv];
        const float b1 = biasV[cv + 16];
#pragma unroll
        for (int i = 0; i < 4; ++i) {
#pragma unroll
            for (int r = 0; r < 4; ++r) {
                int row = m0 + mb + i * 16 + fq * 4 + r;
                if (row < M_) {
                    int b2 = row / L_;
                    int l2 = row - b2 * L_;
                    size_t vb = (size_t)(b2 * H_ + h2) * DH_ * LP_;
                    Vt[vb + (size_t)d2 * LP_ + l2]        = (__bf16)(acc[i][0][r] + b0);
                    Vt[vb + (size_t)(d2 + 16) * LP_ + l2] = (__bf16)(acc[i][1][r] + b1);
                }
            }
        }
    }
}

// ---------------- MFMA flash attention, split-K, plain bf16 QKV ----------------
// QK^T: 1-pass bf16. PV: 1-pass. Zero unpack VALU: frags read directly from LDS.
__global__ __launch_bounds__(256) void attn_mfma_kernel(
    const __bf16* __restrict__ Qb, const __bf16* __restrict__ Kb,
    const __bf16* __restrict__ Vtb, float* __restrict__ Opart,
    float* __restrict__ ml) {
    constexpr int LDP = 72;                   // bf16 row stride (144B)
    constexpr int NT = (L_ + 63) / 64;        // 17
    __shared__ alignas(16) __bf16 Kls[64][LDP];
    __shared__ alignas(16) __bf16 Vls[64][LDP];

    const int tid  = threadIdx.x;
    const int lane = tid & 63;
    const int wv   = tid >> 6;
    const int fr   = lane & 15;
    const int fq   = lane >> 4;
    const int fq8  = fq * 8;

    int bid = blockIdx.x;
    int swz = (bid & 7) * (NSPLIT_ * NQT_ * H_ * B_ / 8) + (bid >> 3);
    const int s   = swz / (NQT_ * H_ * B_);
    int rem = swz - s * (NQT_ * H_ * B_);
    const int qt = rem % NQT_;
    const int bh = rem / NQT_;
    const int h = bh & 7, b = bh >> 3;
    const int q0 = qt * 128 + wv * 32;
    const int T0 = (s == 0) ? 0 : 9;
    const int T1 = (s == 0) ? 9 : NT;
    const size_t obase = (size_t)b * L_ * D_ + h * DH_;

    bf16x8 bqh[2][2];
#pragma unroll
    for (int g = 0; g < 2; ++g) {
        int gq = q0 + 16 * g + fr; if (gq > L_ - 1) gq = L_ - 1;
        const __bf16* qrow = Qb + (size_t)(b * L_ + gq) * D_ + h * DH_;
#pragma unroll
        for (int ss = 0; ss < 2; ++ss)
            bqh[g][ss] = *(const bf16x8*)&qrow[ss * 32 + fq8];
    }

    float m[2] = {-1e30f, -1e30f};
    float lsum[2] = {0.f, 0.f};
    f32x4 oA[2][4];
#pragma unroll
    for (int g = 0; g < 2; ++g)
#pragma unroll
        for (int c = 0; c < 4; ++c) oA[g][c] = (f32x4){0.f, 0.f, 0.f, 0.f};

    const int sr  = tid >> 2;
    const int scb = (tid & 3) * 8;
    const size_t kRowBase = (size_t)(b * L_) * D_ + h * DH_ + scb;
    const size_t vRowBase = ((size_t)bh * DH_ + sr) * LP_ + scb;

    u32x4 kR[2], vR[2];
    {
        int gr = T0 * 64 + sr; if (gr > L_ - 1) gr = L_ - 1;
        const __bf16* kp = Kb + kRowBase + (size_t)gr * D_;
        const __bf16* vp = Vtb + vRowBase + T0 * 64;
        kR[0] = *(const u32x4*)&kp[0];  kR[1] = *(const u32x4*)&kp[32];
        vR[0] = *(const u32x4*)&vp[0];  vR[1] = *(const u32x4*)&vp[32];
        *(u32x4*)&Kls[sr][scb]      = kR[0];
        *(u32x4*)&Kls[sr][scb + 32] = kR[1];
        *(u32x4*)&Vls[sr][scb]      = vR[0];
        *(u32x4*)&Vls[sr][scb + 32] = vR[1];
    }

    for (int t = T0; t < T1; ++t) {
        const int kt = t * 64;
        __syncthreads();

        if (t + 1 < T1) {
            int gr = kt + 64 + sr; if (gr > L_ - 1) gr = L_ - 1;
            const __bf16* kp = Kb + kRowBase + (size_t)gr * D_;
            const __bf16* vp = Vtb + vRowBase + (kt + 64);
            kR[0] = *(const u32x4*)&kp[0];  kR[1] = *(const u32x4*)&kp[32];
            vR[0] = *(const u32x4*)&vp[0];  vR[1] = *(const u32x4*)&vp[32];
        }

        float p0[4][4], p1[4][4];
#pragma unroll
        for (int c = 0; c < 4; ++c) {
            const int row = 16 * c + fr;
            bf16x8 ah0 = *(bf16x8*)&Kls[row][fq8];
            bf16x8 ah1 = *(bf16x8*)&Kls[row][32 + fq8];
#pragma unroll
            for (int g = 0; g < 2; ++g) {
                f32x4 sacc = (f32x4){0.f, 0.f, 0.f, 0.f};
                sacc = __builtin_amdgcn_mfma_f32_16x16x32_bf16(ah0, bqh[g][0], sacc, 0, 0, 0);
                sacc = __builtin_amdgcn_mfma_f32_16x16x32_bf16(ah1, bqh[g][1], sacc, 0, 0, 0);
#pragma unroll
                for (int rr = 0; rr < 4; ++rr) {
                    int k = kt + 16 * c + 4 * fq + rr;
                    float val = (k < L_) ? sacc[rr] * SCALE_ : -1e30f;
                    if (g == 0) p0[c][rr] = val; else p1[c][rr] = val;
                }
            }
        }

        bf16x8 pah[2][2];
#pragma unroll
        for (int g = 0; g < 2; ++g) {
            float (*p)[4] = (g == 0) ? p0 : p1;
            float t0 = p[0][0];
#pragma unroll
            for (int c = 0; c < 4; ++c)
#pragma unroll
                for (int rr = 0; rr < 4; ++rr) t0 = fmaxf(t0, p[c][rr]);
            t0 = fmaxf(t0, __shfl_xor(t0, 16));
            t0 = fmaxf(t0, __shfl_xor(t0, 32));
            float mn = fmaxf(m[g], t0);
            float sclq = __expf(m[g] - mn);
            m[g] = mn;
            float ls = 0.f;
#pragma unroll
            for (int c = 0; c < 4; ++c)
#pragma unroll
                for (int rr = 0; rr < 4; ++rr) {
                    float e = __expf(p[c][rr] - mn);
                    p[c][rr] = e;
                    ls += e;
                }
            ls += __shfl_xor(ls, 16);
            ls += __shfl_xor(ls, 32);
            lsum[g] = lsum[g] * sclq + ls;
#pragma unroll
            for (int rr = 0; rr < 4; ++rr) {
                float sO = __shfl(sclq, 4 * fq + rr);
#pragma unroll
                for (int c2 = 0; c2 < 4; ++c2) oA[g][c2][rr] *= sO;
            }

            uint32_t pqh[4][2];
#pragma unroll
            for (int c = 0; c < 4; ++c) {
                pqh[c][0] = pk2f(p[c][0], p[c][1]);
                pqh[c][1] = pk2f(p[c][2], p[c][3]);
            }
            const int src0 = fr + ((fq & 1) << 5);
            const int src1 = src0 + 16;
            const bool sel = (fq >> 1) != 0;
#pragma unroll
            for (int ss = 0; ss < 2; ++ss) {
                const int c0 = 2 * ss, c1 = 2 * ss + 1;
                uint32_t A0 = (uint32_t)__shfl((int)pqh[c0][0], src0);
                uint32_t A1 = (uint32_t)__shfl((int)pqh[c0][1], src0);
                uint32_t A2 = (uint32_t)__shfl((int)pqh[c0][0], src1);
                uint32_t A3 = (uint32_t)__shfl((int)pqh[c0][1], src1);
                uint32_t B0 = (uint32_t)__shfl((int)pqh[c1][0], src0);
                uint32_t B1 = (uint32_t)__shfl((int)pqh[c1][1], src0);
                uint32_t B2 = (uint32_t)__shfl((int)pqh[c1][0], src1);
                uint32_t B3 = (uint32_t)__shfl((int)pqh[c1][1], src1);
                U4 uh;
                uh.u[0] = sel ? B0 : A0; uh.u[1] = sel ? B1 : A1;
                uh.u[2] = sel ? B2 : A2; uh.u[3] = sel ? B3 : A3;
                pah[g][ss] = uh.f;
            }
        }

#pragma unroll
        for (int c2 = 0; c2 < 4; ++c2) {
            const int row = 16 * c2 + fr;
            bf16x8 vh0 = *(bf16x8*)&Vls[row][fq8];
            bf16x8 vh1 = *(bf16x8*)&Vls[row][32 + fq8];
#pragma unroll
            for (int g = 0; g < 2; ++g) {
                f32x4 o = oA[g][c2];
                o = __builtin_amdgcn_mfma_f32_16x16x32_bf16(pah[g][0], vh0, o, 0, 0, 0);
                o = __builtin_amdgcn_mfma_f32_16x16x32_bf16(pah[g][1], vh1, o, 0, 0, 0);
                oA[g][c2] = o;
            }
        }

        __syncthreads();
        if (t + 1 < T1) {
            *(u32x4*)&Kls[sr][scb]      = kR[0];
            *(u32x4*)&Kls[sr][scb + 32] = kR[1];
            *(u32x4*)&Vls[sr][scb]      = vR[0];
            *(u32x4*)&Vls[sr][scb + 32] = vR[1];
        }
    }

    float* Op = Opart + (size_t)s * M_ * D_;
#pragma unroll
    for (int g = 0; g < 2; ++g) {
#pragma unroll
        for (int rr = 0; rr < 4; ++rr) {
            int row = q0 + 16 * g + 4 * fq + rr;
            if (row < L_) {
#pragma unroll
                for (int c2 = 0; c2 < 4; ++c2)
                    Op[obase + (size_t)row * D_ + 16 * c2 + fr] = oA[g][c2][rr];
            }
        }
        if (fq == 0) {
            int qrow = q0 + 16 * g + fr;
            if (qrow < L_) {
                size_t mlidx = (((size_t)s * B_ + b) * H_ + h) * L_ + qrow;
                ml[mlidx * 2]     = m[g];
                ml[mlidx * 2 + 1] = lsum[g];
            }
        }
    }
}

// ---------------- merge split-K partials -> bf16 (Wo GEMM A-operand) ----------------
__global__ __launch_bounds__(256) void attn_merge_kernel(
    const float* __restrict__ Opart, const float* __restrict__ ml,
    __bf16* __restrict__ Out) {
    int idx = blockIdx.x * 256 + threadIdx.x;
    if (idx >= M_ * 64) return;
    int row = idx >> 6;
    int seg = idx & 63;
    int col0 = seg * 8;
    int h = col0 >> 6;
    int b = row / L_;
    int l = row - b * L_;
    size_t i0 = ((((size_t)0 * B_ + b) * H_ + h) * L_ + l) * 2;
    size_t i1 = ((((size_t)1 * B_ + b) * H_ + h) * L_ + l) * 2;
    float m0 = ml[i0], l0 = ml[i0 + 1];
    float m1 = ml[i1], l1 = ml[i1 + 1];
    float mm = fmaxf(m0, m1);
    float e0 = __expf(m0 - mm), e1 = __expf(m1 - mm);
    float inv = 1.f / (e0 * l0 + e1 * l1);
    float w0 = e0 * inv, w1 = e1 * inv;
    size_t base = (size_t)row * D_ + col0;
    const float* O0 = Opart;
    const float* O1 = Opart + (size_t)M_ * D_;
    float4 a0 = *(const float4*)&O0[base];
    float4 a1 = *(const float4*)&O0[base + 4];
    float4 c0 = *(const float4*)&O1[base];
    float4 c1 = *(const float4*)&O1[base + 4];
    float o0 = w0 * a0.x + w1 * c0.x, o1v = w0 * a0.y + w1 * c0.y;
    float o2 = w0 * a0.z + w1 * c0.z, o3 = w0 * a0.w + w1 * c0.w;
    float o4 = w0 * a1.x + w1 * c1.x, o5 = w0 * a1.y + w1 * c1.y;
    float o6 = w0 * a1.z + w1 * c1.z, o7 = w0 * a1.w + w1 * c1.w;
    U4 u;
    u.u[0] = pk2f(o0, o1v); u.u[1] = pk2f(o2, o3);
    u.u[2] = pk2f(o4, o5);  u.u[3] = pk2f(o6, o7);
    *(u32x4*)&Out[base] = *(u32x4*)&u.u[0];
}

// ---------------- fused residual add + LayerNorm (+ optional bf16 out) ----------------
template <bool HIOUT>
__global__ __launch_bounds__(256) void add_ln_kernel(
    const float* __restrict__ X, const float* __restrict__ Y,
    const float* __restrict__ g, const float* __restrict__ be,
    float* __restrict__ Out, __bf16* __restrict__ Oh) {
    int wave = threadIdx.x >> 6;
    int lane = threadIdx.x & 63;
    int row = blockIdx.x * 4 + wave;
    if (row >= M_) return;
    size_t base = (size_t)row * D_;
    int c0 = lane * 4, c1 = 256 + lane * 4;
    float4 xa = *(const float4*)&X[base + c0];
    float4 xb = *(const float4*)&X[base + c1];
    float4 ya = *(const float4*)&Y[base + c0];
    float4 yb = *(const float4*)&Y[base + c1];
    float v[8] = {xa.x + ya.x, xa.y + ya.y, xa.z + ya.z, xa.w + ya.w,
                  xb.x + yb.x, xb.y + yb.y, xb.z + yb.z, xb.w + yb.w};
    float s = 0.f, s2 = 0.f;
#pragma unroll
    for (int i = 0; i < 8; ++i) { s += v[i]; s2 = fmaf(v[i], v[i], s2); }
#pragma unroll
    for (int off = 32; off > 0; off >>= 1) {
        s  += __shfl_xor(s, off);
        s2 += __shfl_xor(s2, off);
    }
    float mean = s * (1.f / D_);
    float var  = s2 * (1.f / D_) - mean * mean;
    float rstd = rsqrtf(var + EPS_);
    float4 ga = *(const float4*)&g[c0];
    float4 gb = *(const float4*)&g[c1];
    float4 ba = *(const float4*)&be[c0];
    float4 bb = *(const float4*)&be[c1];
    float o[8];
    o[0] = (v[0] - mean) * rstd * ga.x + ba.x;
    o[1] = (v[1] - mean) * rstd * ga.y + ba.y;
    o[2] = (v[2] - mean) * rstd * ga.z + ba.z;
    o[3] = (v[3] - mean) * rstd * ga.w + ba.w;
    o[4] = (v[4] - mean) * rstd * gb.x + bb.x;
    o[5] = (v[5] - mean) * rstd * gb.y + bb.y;
    o[6] = (v[6] - mean) * rstd * gb.z + bb.z;
    o[7] = (v[7] - mean) * rstd * gb.w + bb.w;
    *(float4*)&Out[base + c0] = make_float4(o[0], o[1], o[2], o[3]);
    *(float4*)&Out[base + c1] = make_float4(o[4], o[5], o[6], o[7]);
    if (HIOUT) {
        bf16x4 h0, h1;
#pragma unroll
        for (int i = 0; i < 4; ++i) {
            h0[i] = (__bf16)o[i];
            h1[i] = (__bf16)o[4 + i];
        }
        *(bf16x4*)&Oh[base + c0] = h0;
        *(bf16x4*)&Oh[base + c1] = h1;
    }
}

// ---------------- launch ----------------
extern "C" void kernel_launch(void* const* d_in, const int* in_sizes, int n_in,
                              void* d_out, int out_size, void* d_ws, size_t ws_size,
                              hipStream_t stream) {
    const float* embed1 = (const float*)d_in[0];
    const float* embed2 = (const float*)d_in[1];
    const float* cls    = (const float*)d_in[2];
    const float* Wq = (const float*)d_in[3];
    const float* bq = (const float*)d_in[4];
    const float* Wk = (const float*)d_in[5];
    const float* bk = (const float*)d_in[6];
    const float* Wv = (const float*)d_in[7];
    const float* bv = (const float*)d_in[8];
    const float* Wo = (const float*)d_in[9];
    const float* bo = (const float*)d_in[10];
    const float* ln1g = (const float*)d_in[11];
    const float* ln1b = (const float*)d_in[12];
    const float* W1 = (const float*)d_in[13];
    const float* b1 = (const float*)d_in[14];
    const float* W2 = (const float*)d_in[15];
    const float* b2 = (const float*)d_in[16];
    const float* ln2g = (const float*)d_in[17];
    const float* ln2b = (const float*)d_in[18];

    const size_t SZ = (size_t)M_ * D_;        // 4,198,400 floats
    float* ws = (float*)d_ws;
    float* X   = ws;                           // [0,SZ) fp32 residual stream
    __bf16* Xh = (__bf16*)(ws + SZ);           // [SZ,1.5SZ) bf16 of X
    __bf16* X2h = (__bf16*)(ws + SZ + SZ / 2); // [1.5SZ,2SZ) bf16 of X2
    float* Tb  = ws + 2 * SZ;                  // [2SZ,3SZ): fp32 scratch (X2 setup, FFN2 out)
    __bf16* Tbh = (__bf16*)(ws + 2 * SZ + SZ / 2); // merge out (attn phase; Tb fp32 dead then)
    __bf16* Qbh = (__bf16*)(ws + 3 * SZ);      // [3SZ,3.5SZ) bf16 Q (attn phase)
    float* WoOut  = (float*)(ws + 3 * SZ);     // aliases Qbh region (dead after attn)
    __bf16* Kbh = (__bf16*)(ws + 4 * SZ);      // [4SZ,4.5SZ) bf16 K
    __bf16* Vtb = (__bf16*)(ws + 5 * SZ);      // [5SZ,~5.54SZ) bf16 Vt (attn phase)
    __bf16* Hbh = (__bf16*)(ws + 5 * SZ);      // [5SZ,7SZ) bf16 [M,DFF] FFN phase (aliases Vtb)
    float* mlBuf   = ws + 6 * SZ + SZ / 2;     // stats (attn phase) -- past Vt end, dead by FFN
    float* Opart   = ws + 7 * SZ;              // [7SZ,9SZ) 2 partial O (attn phase)
    __bf16* wreg = (__bf16*)(ws + 9 * SZ);     // bf16 weights

    const size_t NQl = (size_t)D_ * D_;                // 262144 per layer
    const size_t NQ  = (size_t)NLAYER_ * NQl;          // 524288
    const size_t NF  = (size_t)NLAYER_ * DFF_ * D_;    // 2097152
    __bf16* Wqh  = wreg;                 // NQ
    __bf16* Wkvh = Wqh + NQ;             // 2*NQ  [NLAYER][1024][512]
    __bf16* Woh  = Wkvh + 2 * NQ;        // NQ
    __bf16* W1h  = Woh + NQ;             // NF
    __bf16* W2h  = W1h + NF;             // NF

    tobf16_kernel<<<(int)(NQ / 4 + 255) / 256, 256, 0, stream>>>(Wq, Wqh, (int)(NQ / 4));
    tobf16_kernel<<<(int)(NQ / 4 + 255) / 256, 256, 0, stream>>>(Wo, Woh, (int)(NQ / 4));
    tobf16_kernel<<<(int)(NF / 4 + 255) / 256, 256, 0, stream>>>(W1, W1h, (int)(NF / 4));
    tobf16_kernel<<<(int)(NF / 4 + 255) / 256, 256, 0, stream>>>(W2, W2h, (int)(NF / 4));
    for (int l = 0; l < NLAYER_; ++l) {
        tobf16_kernel<<<(int)(NQl / 4 + 255) / 256, 256, 0, stream>>>(
            Wk + l * NQl, Wkvh + l * 2 * NQl, (int)(NQl / 4));
        tobf16_kernel<<<(int)(NQl / 4 + 255) / 256, 256, 0, stream>>>(
            Wv + l * NQl, Wkvh + l * 2 * NQl + NQl, (int)(NQl / 4));
    }

    // build X (fp32, persistent) and X2 (fp32 in Tb scratch, converted once)
    float* X2tmp = Tb;
    write_cls_kernel<<<(B_ * D_) / 256, 256, 0, stream>>>(cls, X, X2tmp);
    transpose_embed_kernel<<<dim3(L0_ / 32, D_ / 32, B_), dim3(32, 8), 0, stream>>>(embed1, X);
    transpose_embed_kernel<<<dim3(L0_ / 32, D_ / 32, B_), dim3(32, 8), 0, stream>>>(embed2, X2tmp);
    tobf16_kernel<<<(int)(SZ / 4 + 255) / 256, 256, 0, stream>>>(X, Xh, (int)(SZ / 4));
    tobf16_kernel<<<(int)(SZ / 4 + 255) / 256, 256, 0, stream>>>(X2tmp, X2h, (int)(SZ / 4));

    const int GM = (M_ + 127) / 128;         // 65
    const int g512  = GM * (512 / 64);       // 520
    const int g1024 = GM * (1024 / 64);      // 1040
    const int g2048 = GM * (2048 / 64);      // 2080
    const int gpad  = (B_ * H_ * DH_ * (LP_ - L_) + 255) / 256;
    const int gmerge = (M_ * 64 + 255) / 256;

    for (int l = 0; l < NLAYER_; ++l) {
        const size_t oQ = (size_t)l * NQl;
        const size_t oF = (size_t)l * DFF_ * D_;

        gemm_mfma_kernel<false, 2><<<g512, 256, 0, stream>>>(
            Xh, Wqh + oQ, bq + l * D_, nullptr, Qbh, M_, D_, D_);
        gemm_kv_kernel<<<g1024, 256, 0, stream>>>(
            X2h, Wkvh + l * 2 * NQl, bk + l * D_, bv + l * D_, Kbh, Vtb);
        zero_vt_pad_kernel<<<gpad, 256, 0, stream>>>(Vtb);

        attn_mfma_kernel<<<NSPLIT_ * NQT_ * H_ * B_, 256, 0, stream>>>(
            Qbh, Kbh, Vtb, Opart, mlBuf);
        attn_merge_kernel<<<gmerge, 256, 0, stream>>>(Opart, mlBuf, Tbh);

        gemm_mfma_kernel<false, 0><<<g512, 256, 0, stream>>>(
            Tbh, Woh + oQ, bo + l * D_, WoOut, nullptr, M_, D_, D_);

        add_ln_kernel<true><<<(M_ + 3) / 4, 256, 0, stream>>>(
            X, WoOut, ln1g + l * D_, ln1b + l * D_, X, Xh);

        gemm_mfma_kernel<true, 2><<<g2048, 256, 0, stream>>>(
            Xh, W1h + oF, b1 + l * DFF_, nullptr, Hbh, M_, DFF_, D_);
        gemm_mfma_kernel<false, 0><<<g512, 256, 0, stream>>>(
            Hbh, W2h + oF, b2 + l * D_, Tb, nullptr, M_, D_, DFF_);

        if (l == NLAYER_ - 1) {
            add_ln_kernel<false><<<(M_ + 3) / 4, 256, 0, stream>>>(
                X, Tb, ln2g + l * D_, ln2b + l * D_, (float*)d_out, nullptr);
        } else {
            add_ln_kernel<true><<<(M_ + 3) / 4, 256, 0, stream>>>(
                X, Tb, ln2g + l * D_, ln2b + l * D_, X, Xh);
        }
    }
}

// Round 22
// 554.060 us; speedup vs baseline: 1.3266x; 1.0427x over previous
//
#include <hip/hip_runtime.h>
#include <hip/hip_bf16.h>

// ---------------- problem constants ----------------
constexpr int B_   = 8;
constexpr int D_   = 512;
constexpr int L0_  = 1024;
constexpr int L_   = 1025;          // L0 + cls
constexpr int H_   = 8;
constexpr int DH_  = 64;
constexpr int DFF_ = 2048;
constexpr int NLAYER_ = 2;
constexpr int M_   = B_ * L_;       // 8200 rows
constexpr int LP_  = 1088;          // padded L for Vt (17*64)
constexpr int NQT_ = 9;             // ceil(L/128) attn q-tiles
constexpr int NSPLIT_ = 2;          // K-range partitions (flash-decoding)
constexpr float EPS_   = 1e-6f;
constexpr float SCALE_ = 0.125f;    // 1/sqrt(64)

#define DEV_INLINE __device__ __forceinline__

typedef __attribute__((ext_vector_type(8))) __bf16 bf16x8;
typedef __attribute__((ext_vector_type(4))) __bf16 bf16x4;
typedef __attribute__((ext_vector_type(4))) float  f32x4;
typedef __attribute__((ext_vector_type(4))) unsigned int u32x4;

union U4 { uint32_t u[4]; bf16x8 f; };

DEV_INLINE float gelu_exact(float x) {
    return 0.5f * x * (1.f + erff(x * 0.70710678118654752f));
}

DEV_INLINE uint16_t bfbits(float v) {
    __bf16 h = (__bf16)v;
    return __builtin_bit_cast(uint16_t, h);
}
DEV_INLINE uint32_t pk2f(float a, float b) {
    return (uint32_t)bfbits(a) | ((uint32_t)bfbits(b) << 16);
}
DEV_INLINE float bf2f(uint32_t bits16) {           // low 16 bits = bf16
    uint32_t u = bits16 << 16;
    return __builtin_bit_cast(float, u);
}

// ---------------- fp32 -> bf16 ----------------
__global__ __launch_bounds__(256) void tobf16_kernel(
    const float* __restrict__ src, __bf16* __restrict__ dst, int n4) {
    int i = blockIdx.x * 256 + threadIdx.x;
    if (i >= n4) return;
    float4 v = *(const float4*)&src[i * 4];
    bf16x4 h;
    h[0] = (__bf16)v.x; h[1] = (__bf16)v.y;
    h[2] = (__bf16)v.z; h[3] = (__bf16)v.w;
    *(bf16x4*)&dst[i * 4] = h;
}

// ---------------- zero Vt pad tokens (l = L_..LP_-1), bf16 ----------------
// CRITICAL: pad tokens feed PV MFMA with P=0; garbage bits can alias bf16
// Inf/NaN and 0*Inf = NaN (R10 failure). Must be zeroed every layer.
__global__ __launch_bounds__(256) void zero_vt_pad_kernel(__bf16* __restrict__ Vt) {
    constexpr int PAD = LP_ - L_;                 // 63
    int idx = blockIdx.x * 256 + threadIdx.x;
    int total = B_ * H_ * DH_ * PAD;
    if (idx >= total) return;
    int row = idx / PAD;
    int c   = idx - row * PAD;
    Vt[(size_t)row * LP_ + L_ + c] = (__bf16)0.f;
}

// ---------------- build x1/x2 ----------------
__global__ __launch_bounds__(256) void write_cls_kernel(
    const float* __restrict__ cls, float* __restrict__ X1, float* __restrict__ X2) {
    int idx = blockIdx.x * 256 + threadIdx.x;
    int b = idx >> 9;
    int d = idx & 511;
    float v = cls[d];
    X1[(size_t)b * L_ * D_ + d] = v;
    X2[(size_t)b * L_ * D_ + d] = v;
}

// embed [B, D, L0] -> X rows 1..L0
__global__ __launch_bounds__(256) void transpose_embed_kernel(
    const float* __restrict__ e, float* __restrict__ X) {
    __shared__ float tile[32][33];
    int b  = blockIdx.z;
    int i0 = blockIdx.x * 32;
    int d0 = blockIdx.y * 32;
    int tx = threadIdx.x;
    int ty = threadIdx.y;
#pragma unroll
    for (int j = 0; j < 32; j += 8)
        tile[ty + j][tx] = e[((size_t)b * D_ + d0 + ty + j) * L0_ + i0 + tx];
    __syncthreads();
#pragma unroll
    for (int j = 0; j < 32; j += 8)
        X[((size_t)b * L_ + 1 + i0 + ty + j) * D_ + d0 + tx] = tile[tx][ty + j];
}

// ---------------- pure bf16 MFMA GEMM, BK=64 ----------------
// C = A*W^T + bias; A and W both plain bf16 in global.
// Reg-prefetch staging (R16 structure), BK=64 halves barrier count.
// OUTMODE: 0 = fp32, 2 = bf16.
template <bool GELU, int OUTMODE>
__global__ __launch_bounds__(256) void gemm_mfma_kernel(
    const __bf16* __restrict__ A, const __bf16* __restrict__ Wh,
    const float* __restrict__ bias, float* __restrict__ C,
    __bf16* __restrict__ Ch, int M, int N, int K) {
    constexpr int BM = 128, BN = 64, BK = 64;
    constexpr int LDK = BK + 8;     // 72
    __shared__ alignas(16) __bf16 Ahs[BM][LDK];
    __shared__ alignas(16) __bf16 Bhs[BN][LDK];

    const int GM = (M + BM - 1) / BM;
    const int nwg = gridDim.x;
    int bid = blockIdx.x;
    {
        int q = nwg >> 3, r = nwg & 7;
        int xcd = bid & 7, pos = bid >> 3;
        bid = (xcd < r) ? xcd * (q + 1) + pos
                        : r * (q + 1) + (xcd - r) * q + pos;
    }
    const int bn = bid / GM;
    const int bm = bid % GM;
    const int m0 = bm * BM;
    const int n0 = bn * BN;

    const int tid  = threadIdx.x;
    const int lane = tid & 63;
    const int wv   = tid >> 6;
    const int wr   = wv >> 1;
    const int wc   = wv & 1;
    const int fr   = lane & 15;
    const int fq   = lane >> 4;
    const int fq8  = fq * 8;
    const int mb   = wr * 64;
    const int nb   = wc * 32;

    // staging: row = tid>>2 (0..63), cols scol..scol+15 (16 bf16 = 2 chunks)
    const int srow = tid >> 2;
    const int scol = (tid & 3) * 16;
    size_t aOff[2];
#pragma unroll
    for (int rep = 0; rep < 2; ++rep) {
        int r = m0 + srow + rep * 64;
        if (r > M - 1) r = M - 1;
        aOff[rep] = (size_t)r * K + scol;
    }
    const size_t wOff = (size_t)(n0 + srow) * K + scol;

    f32x4 acc[4][2];
#pragma unroll
    for (int i = 0; i < 4; ++i)
#pragma unroll
        for (int j = 0; j < 2; ++j) acc[i][j] = (f32x4){0.f, 0.f, 0.f, 0.f};

    const int nk = K / BK;
    u32x4 aR[2][2], wR[2];
#pragma unroll
    for (int rep = 0; rep < 2; ++rep) {
        aR[rep][0] = *(const u32x4*)&A[aOff[rep]];
        aR[rep][1] = *(const u32x4*)&A[aOff[rep] + 8];
    }
    wR[0] = *(const u32x4*)&Wh[wOff];
    wR[1] = *(const u32x4*)&Wh[wOff + 8];

    for (int kt = 0; kt < nk; ++kt) {
#pragma unroll
        for (int rep = 0; rep < 2; ++rep) {
            *(u32x4*)&Ahs[srow + rep * 64][scol]     = aR[rep][0];
            *(u32x4*)&Ahs[srow + rep * 64][scol + 8] = aR[rep][1];
        }
        *(u32x4*)&Bhs[srow][scol]     = wR[0];
        *(u32x4*)&Bhs[srow][scol + 8] = wR[1];
        __syncthreads();

        if (kt + 1 < nk) {
            int k0 = (kt + 1) * BK;
#pragma unroll
            for (int rep = 0; rep < 2; ++rep) {
                aR[rep][0] = *(const u32x4*)&A[aOff[rep] + k0];
                aR[rep][1] = *(const u32x4*)&A[aOff[rep] + k0 + 8];
            }
            wR[0] = *(const u32x4*)&Wh[wOff + k0];
            wR[1] = *(const u32x4*)&Wh[wOff + k0 + 8];
        }

#pragma unroll
        for (int ks = 0; ks < 2; ++ks) {
            bf16x8 ah[4], bh[2];
#pragma unroll
            for (int i = 0; i < 4; ++i)
                ah[i] = *(bf16x8*)&Ahs[mb + i * 16 + fr][ks * 32 + fq8];
#pragma unroll
            for (int j = 0; j < 2; ++j)
                bh[j] = *(bf16x8*)&Bhs[nb + j * 16 + fr][ks * 32 + fq8];
#pragma unroll
            for (int i = 0; i < 4; ++i)
#pragma unroll
                for (int j = 0; j < 2; ++j)
                    acc[i][j] = __builtin_amdgcn_mfma_f32_16x16x32_bf16(ah[i], bh[j], acc[i][j], 0, 0, 0);
        }
        __syncthreads();
    }

    const int ccol0 = n0 + nb + fr;
    const float b0 = bias[ccol0];
    const float b1 = bias[ccol0 + 16];
#pragma unroll
    for (int i = 0; i < 4; ++i) {
#pragma unroll
        for (int r = 0; r < 4; ++r) {
            int row = m0 + mb + i * 16 + fq * 4 + r;
            if (row < M) {
                float v0 = acc[i][0][r] + b0;
                float v1 = acc[i][1][r] + b1;
                if (GELU) { v0 = gelu_exact(v0); v1 = gelu_exact(v1); }
                if (OUTMODE == 2) {
                    Ch[(size_t)row * N + ccol0]      = (__bf16)v0;
                    Ch[(size_t)row * N + ccol0 + 16] = (__bf16)v1;
                } else {
                    C[(size_t)row * N + ccol0]      = v0;
                    C[(size_t)row * N + ccol0 + 16] = v1;
                }
            }
        }
    }
}

// ---------------- fused K+V GEMM, 1-pass bf16, BK=64 (V stored transposed) ----------------
__global__ __launch_bounds__(256) void gemm_kv_kernel(
    const __bf16* __restrict__ A, const __bf16* __restrict__ Wh,
    const float* __restrict__ biasK, const float* __restrict__ biasV,
    __bf16* __restrict__ Kb, __bf16* __restrict__ Vt) {
    constexpr int BM = 128, BN = 64, BK = 64, K = 512;
    constexpr int LDK = BK + 8;
    __shared__ alignas(16) __bf16 Ahs[BM][LDK];
    __shared__ alignas(16) __bf16 Bhs[BN][LDK];

    const int GM = (M_ + BM - 1) / BM;
    const int nwg = gridDim.x;
    int bid = blockIdx.x;
    {
        int q = nwg >> 3, r = nwg & 7;
        int xcd = bid & 7, pos = bid >> 3;
        bid = (xcd < r) ? xcd * (q + 1) + pos
                        : r * (q + 1) + (xcd - r) * q + pos;
    }
    const int bn = bid / GM;
    const int bm = bid % GM;
    const int m0 = bm * BM;
    const int n0 = bn * BN;

    const int tid  = threadIdx.x;
    const int lane = tid & 63;
    const int wv   = tid >> 6;
    const int wr   = wv >> 1;
    const int wc   = wv & 1;
    const int fr   = lane & 15;
    const int fq   = lane >> 4;
    const int fq8  = fq * 8;
    const int mb   = wr * 64;
    const int nb   = wc * 32;

    const int srow = tid >> 2;
    const int scol = (tid & 3) * 16;
    size_t aOff[2];
#pragma unroll
    for (int rep = 0; rep < 2; ++rep) {
        int r = m0 + srow + rep * 64;
        if (r > M_ - 1) r = M_ - 1;
        aOff[rep] = (size_t)r * K + scol;
    }
    const size_t wOff = (size_t)(n0 + srow) * K + scol;

    f32x4 acc[4][2];
#pragma unroll
    for (int i = 0; i < 4; ++i)
#pragma unroll
        for (int j = 0; j < 2; ++j) acc[i][j] = (f32x4){0.f, 0.f, 0.f, 0.f};

    const int nk = K / BK;
    u32x4 aR[2][2], wR[2];
#pragma unroll
    for (int rep = 0; rep < 2; ++rep) {
        aR[rep][0] = *(const u32x4*)&A[aOff[rep]];
        aR[rep][1] = *(const u32x4*)&A[aOff[rep] + 8];
    }
    wR[0] = *(const u32x4*)&Wh[wOff];
    wR[1] = *(const u32x4*)&Wh[wOff + 8];

    for (int kt = 0; kt < nk; ++kt) {
#pragma unroll
        for (int rep = 0; rep < 2; ++rep) {
            *(u32x4*)&Ahs[srow + rep * 64][scol]     = aR[rep][0];
            *(u32x4*)&Ahs[srow + rep * 64][scol + 8] = aR[rep][1];
        }
        *(u32x4*)&Bhs[srow][scol]     = wR[0];
        *(u32x4*)&Bhs[srow][scol + 8] = wR[1];
        __syncthreads();

        if (kt + 1 < nk) {
            int k0 = (kt + 1) * BK;
#pragma unroll
            for (int rep = 0; rep < 2; ++rep) {
                aR[rep][0] = *(const u32x4*)&A[aOff[rep] + k0];
                aR[rep][1] = *(const u32x4*)&A[aOff[rep] + k0 + 8];
            }
            wR[0] = *(const u32x4*)&Wh[wOff + k0];
            wR[1] = *(const u32x4*)&Wh[wOff + k0 + 8];
        }

#pragma unroll
        for (int ks = 0; ks < 2; ++ks) {
            bf16x8 ah[4], bh[2];
#pragma unroll
            for (int i = 0; i < 4; ++i)
                ah[i] = *(bf16x8*)&Ahs[mb + i * 16 + fr][ks * 32 + fq8];
#pragma unroll
            for (int j = 0; j < 2; ++j)
                bh[j] = *(bf16x8*)&Bhs[nb + j * 16 + fr][ks * 32 + fq8];
#pragma unroll
            for (int i = 0; i < 4; ++i)
#pragma unroll
                for (int j = 0; j < 2; ++j)
                    acc[i][j] = __builtin_amdgcn_mfma_f32_16x16x32_bf16(ah[i], bh[j], acc[i][j], 0, 0, 0);
        }
        __syncthreads();
    }

    const int ccol0 = n0 + nb + fr;
    if (n0 < 512) {
        const float b0 = biasK[ccol0];
        const float b1 = biasK[ccol0 + 16];
#pragma unroll
        for (int i = 0; i < 4; ++i) {
#pragma unroll
            for (int r = 0; r < 4; ++r) {
                int row = m0 + mb + i * 16 + fq * 4 + r;
                if (row < M_) {
                    Kb[(size_t)row * 512 + ccol0]      = (__bf16)(acc[i][0][r] + b0);
                    Kb[(size_t)row * 512 + ccol0 + 16] = (__bf16)(acc[i][1][r] + b1);
                }
            }
        }
    } else {
        const int cv = ccol0 - 512;
        const int h2 = cv >> 6, d2 = cv & 63;
        const float b0 = biasV[cv];
        const float b1 = biasV[cv + 16];
#pragma unroll
        for (int i = 0; i < 4; ++i) {
#pragma unroll
            for (int r = 0; r < 4; ++r) {
                int row = m0 + mb + i * 16 + fq * 4 + r;
                if (row < M_) {
                    int b2 = row / L_;
                    int l2 = row - b2 * L_;
                    size_t vb = (size_t)(b2 * H_ + h2) * DH_ * LP_;
                    Vt[vb + (size_t)d2 * LP_ + l2]        = (__bf16)(acc[i][0][r] + b0);
                    Vt[vb + (size_t)(d2 + 16) * LP_ + l2] = (__bf16)(acc[i][1][r] + b1);
                }
            }
        }
    }
}

// ---------------- MFMA flash attention, split-K, plain bf16 QKV ----------------
// QK^T: 1-pass bf16. PV: 1-pass. Partial O written as bf16 (2^-9 rel, merged in fp32).
__global__ __launch_bounds__(256) void attn_mfma_kernel(
    const __bf16* __restrict__ Qb, const __bf16* __restrict__ Kb,
    const __bf16* __restrict__ Vtb, __bf16* __restrict__ Opart,
    float* __restrict__ ml) {
    constexpr int LDP = 72;                   // bf16 row stride (144B)
    constexpr int NT = (L_ + 63) / 64;        // 17
    __shared__ alignas(16) __bf16 Kls[64][LDP];
    __shared__ alignas(16) __bf16 Vls[64][LDP];

    const int tid  = threadIdx.x;
    const int lane = tid & 63;
    const int wv   = tid >> 6;
    const int fr   = lane & 15;
    const int fq   = lane >> 4;
    const int fq8  = fq * 8;

    int bid = blockIdx.x;
    int swz = (bid & 7) * (NSPLIT_ * NQT_ * H_ * B_ / 8) + (bid >> 3);
    const int s   = swz / (NQT_ * H_ * B_);
    int rem = swz - s * (NQT_ * H_ * B_);
    const int qt = rem % NQT_;
    const int bh = rem / NQT_;
    const int h = bh & 7, b = bh >> 3;
    const int q0 = qt * 128 + wv * 32;
    const int T0 = (s == 0) ? 0 : 9;
    const int T1 = (s == 0) ? 9 : NT;
    const size_t obase = (size_t)b * L_ * D_ + h * DH_;

    bf16x8 bqh[2][2];
#pragma unroll
    for (int g = 0; g < 2; ++g) {
        int gq = q0 + 16 * g + fr; if (gq > L_ - 1) gq = L_ - 1;
        const __bf16* qrow = Qb + (size_t)(b * L_ + gq) * D_ + h * DH_;
#pragma unroll
        for (int ss = 0; ss < 2; ++ss)
            bqh[g][ss] = *(const bf16x8*)&qrow[ss * 32 + fq8];
    }

    float m[2] = {-1e30f, -1e30f};
    float lsum[2] = {0.f, 0.f};
    f32x4 oA[2][4];
#pragma unroll
    for (int g = 0; g < 2; ++g)
#pragma unroll
        for (int c = 0; c < 4; ++c) oA[g][c] = (f32x4){0.f, 0.f, 0.f, 0.f};

    const int sr  = tid >> 2;
    const int scb = (tid & 3) * 8;
    const size_t kRowBase = (size_t)(b * L_) * D_ + h * DH_ + scb;
    const size_t vRowBase = ((size_t)bh * DH_ + sr) * LP_ + scb;

    u32x4 kR[2], vR[2];
    {
        int gr = T0 * 64 + sr; if (gr > L_ - 1) gr = L_ - 1;
        const __bf16* kp = Kb + kRowBase + (size_t)gr * D_;
        const __bf16* vp = Vtb + vRowBase + T0 * 64;
        kR[0] = *(const u32x4*)&kp[0];  kR[1] = *(const u32x4*)&kp[32];
        vR[0] = *(const u32x4*)&vp[0];  vR[1] = *(const u32x4*)&vp[32];
        *(u32x4*)&Kls[sr][scb]      = kR[0];
        *(u32x4*)&Kls[sr][scb + 32] = kR[1];
        *(u32x4*)&Vls[sr][scb]      = vR[0];
        *(u32x4*)&Vls[sr][scb + 32] = vR[1];
    }

    for (int t = T0; t < T1; ++t) {
        const int kt = t * 64;
        __syncthreads();

        if (t + 1 < T1) {
            int gr = kt + 64 + sr; if (gr > L_ - 1) gr = L_ - 1;
            const __bf16* kp = Kb + kRowBase + (size_t)gr * D_;
            const __bf16* vp = Vtb + vRowBase + (kt + 64);
            kR[0] = *(const u32x4*)&kp[0];  kR[1] = *(const u32x4*)&kp[32];
            vR[0] = *(const u32x4*)&vp[0];  vR[1] = *(const u32x4*)&vp[32];
        }

        float p0[4][4], p1[4][4];
#pragma unroll
        for (int c = 0; c < 4; ++c) {
            const int row = 16 * c + fr;
            bf16x8 ah0 = *(bf16x8*)&Kls[row][fq8];
            bf16x8 ah1 = *(bf16x8*)&Kls[row][32 + fq8];
#pragma unroll
            for (int g = 0; g < 2; ++g) {
                f32x4 sacc = (f32x4){0.f, 0.f, 0.f, 0.f};
                sacc = __builtin_amdgcn_mfma_f32_16x16x32_bf16(ah0, bqh[g][0], sacc, 0, 0, 0);
                sacc = __builtin_amdgcn_mfma_f32_16x16x32_bf16(ah1, bqh[g][1], sacc, 0, 0, 0);
#pragma unroll
                for (int rr = 0; rr < 4; ++rr) {
                    int k = kt + 16 * c + 4 * fq + rr;
                    float val = (k < L_) ? sacc[rr] * SCALE_ : -1e30f;
                    if (g == 0) p0[c][rr] = val; else p1[c][rr] = val;
                }
            }
        }

        bf16x8 pah[2][2];
#pragma unroll
        for (int g = 0; g < 2; ++g) {
            float (*p)[4] = (g == 0) ? p0 : p1;
            float t0 = p[0][0];
#pragma unroll
            for (int c = 0; c < 4; ++c)
#pragma unroll
                for (int rr = 0; rr < 4; ++rr) t0 = fmaxf(t0, p[c][rr]);
            t0 = fmaxf(t0, __shfl_xor(t0, 16));
            t0 = fmaxf(t0, __shfl_xor(t0, 32));
            float mn = fmaxf(m[g], t0);
            float sclq = __expf(m[g] - mn);
            m[g] = mn;
            float ls = 0.f;
#pragma unroll
            for (int c = 0; c < 4; ++c)
#pragma unroll
                for (int rr = 0; rr < 4; ++rr) {
                    float e = __expf(p[c][rr] - mn);
                    p[c][rr] = e;
                    ls += e;
                }
            ls += __shfl_xor(ls, 16);
            ls += __shfl_xor(ls, 32);
            lsum[g] = lsum[g] * sclq + ls;
#pragma unroll
            for (int rr = 0; rr < 4; ++rr) {
                float sO = __shfl(sclq, 4 * fq + rr);
#pragma unroll
                for (int c2 = 0; c2 < 4; ++c2) oA[g][c2][rr] *= sO;
            }

            uint32_t pqh[4][2];
#pragma unroll
            for (int c = 0; c < 4; ++c) {
                pqh[c][0] = pk2f(p[c][0], p[c][1]);
                pqh[c][1] = pk2f(p[c][2], p[c][3]);
            }
            const int src0 = fr + ((fq & 1) << 5);
            const int src1 = src0 + 16;
            const bool sel = (fq >> 1) != 0;
#pragma unroll
            for (int ss = 0; ss < 2; ++ss) {
                const int c0 = 2 * ss, c1 = 2 * ss + 1;
                uint32_t A0 = (uint32_t)__shfl((int)pqh[c0][0], src0);
                uint32_t A1 = (uint32_t)__shfl((int)pqh[c0][1], src0);
                uint32_t A2 = (uint32_t)__shfl((int)pqh[c0][0], src1);
                uint32_t A3 = (uint32_t)__shfl((int)pqh[c0][1], src1);
                uint32_t B0 = (uint32_t)__shfl((int)pqh[c1][0], src0);
                uint32_t B1 = (uint32_t)__shfl((int)pqh[c1][1], src0);
                uint32_t B2 = (uint32_t)__shfl((int)pqh[c1][0], src1);
                uint32_t B3 = (uint32_t)__shfl((int)pqh[c1][1], src1);
                U4 uh;
                uh.u[0] = sel ? B0 : A0; uh.u[1] = sel ? B1 : A1;
                uh.u[2] = sel ? B2 : A2; uh.u[3] = sel ? B3 : A3;
                pah[g][ss] = uh.f;
            }
        }

#pragma unroll
        for (int c2 = 0; c2 < 4; ++c2) {
            const int row = 16 * c2 + fr;
            bf16x8 vh0 = *(bf16x8*)&Vls[row][fq8];
            bf16x8 vh1 = *(bf16x8*)&Vls[row][32 + fq8];
#pragma unroll
            for (int g = 0; g < 2; ++g) {
                f32x4 o = oA[g][c2];
                o = __builtin_amdgcn_mfma_f32_16x16x32_bf16(pah[g][0], vh0, o, 0, 0, 0);
                o = __builtin_amdgcn_mfma_f32_16x16x32_bf16(pah[g][1], vh1, o, 0, 0, 0);
                oA[g][c2] = o;
            }
        }

        __syncthreads();
        if (t + 1 < T1) {
            *(u32x4*)&Kls[sr][scb]      = kR[0];
            *(u32x4*)&Kls[sr][scb + 32] = kR[1];
            *(u32x4*)&Vls[sr][scb]      = vR[0];
            *(u32x4*)&Vls[sr][scb + 32] = vR[1];
        }
    }

    // ---- epilogue: bf16 unnormalized partial O + per-q stats ----
    __bf16* Op = Opart + (size_t)s * M_ * D_;
#pragma unroll
    for (int g = 0; g < 2; ++g) {
#pragma unroll
        for (int rr = 0; rr < 4; ++rr) {
            int row = q0 + 16 * g + 4 * fq + rr;
            if (row < L_) {
#pragma unroll
                for (int c2 = 0; c2 < 4; ++c2)
                    Op[obase + (size_t)row * D_ + 16 * c2 + fr] = (__bf16)oA[g][c2][rr];
            }
        }
        if (fq == 0) {
            int qrow = q0 + 16 * g + fr;
            if (qrow < L_) {
                size_t mlidx = (((size_t)s * B_ + b) * H_ + h) * L_ + qrow;
                ml[mlidx * 2]     = m[g];
                ml[mlidx * 2 + 1] = lsum[g];
            }
        }
    }
}

// ---------------- merge split-K partials (bf16 in) -> bf16 (Wo GEMM A-operand) ----------------
__global__ __launch_bounds__(256) void attn_merge_kernel(
    const __bf16* __restrict__ Opart, const float* __restrict__ ml,
    __bf16* __restrict__ Out) {
    int idx = blockIdx.x * 256 + threadIdx.x;
    if (idx >= M_ * 64) return;
    int row = idx >> 6;
    int seg = idx & 63;
    int col0 = seg * 8;
    int h = col0 >> 6;
    int b = row / L_;
    int l = row - b * L_;
    size_t i0 = ((((size_t)0 * B_ + b) * H_ + h) * L_ + l) * 2;
    size_t i1 = ((((size_t)1 * B_ + b) * H_ + h) * L_ + l) * 2;
    float m0 = ml[i0], l0 = ml[i0 + 1];
    float m1 = ml[i1], l1 = ml[i1 + 1];
    float mm = fmaxf(m0, m1);
    float e0 = __expf(m0 - mm), e1 = __expf(m1 - mm);
    float inv = 1.f / (e0 * l0 + e1 * l1);
    float w0 = e0 * inv, w1 = e1 * inv;
    size_t base = (size_t)row * D_ + col0;
    const __bf16* O0 = Opart;
    const __bf16* O1 = Opart + (size_t)M_ * D_;
    u32x4 a = *(const u32x4*)&O0[base];
    u32x4 c = *(const u32x4*)&O1[base];
    U4 u;
#pragma unroll
    for (int i = 0; i < 4; ++i) {
        float a0 = bf2f(a[i] & 0xffffu), a1 = bf2f(a[i] >> 16);
        float c0 = bf2f(c[i] & 0xffffu), c1 = bf2f(c[i] >> 16);
        u.u[i] = pk2f(w0 * a0 + w1 * c0, w0 * a1 + w1 * c1);
    }
    *(u32x4*)&Out[base] = *(u32x4*)&u.u[0];
}

// ---------------- fused residual add + LayerNorm (+ optional bf16 out) ----------------
template <bool HIOUT>
__global__ __launch_bounds__(256) void add_ln_kernel(
    const float* __restrict__ X, const float* __restrict__ Y,
    const float* __restrict__ g, const float* __restrict__ be,
    float* __restrict__ Out, __bf16* __restrict__ Oh) {
    int wave = threadIdx.x >> 6;
    int lane = threadIdx.x & 63;
    int row = blockIdx.x * 4 + wave;
    if (row >= M_) return;
    size_t base = (size_t)row * D_;
    int c0 = lane * 4, c1 = 256 + lane * 4;
    float4 xa = *(const float4*)&X[base + c0];
    float4 xb = *(const float4*)&X[base + c1];
    float4 ya = *(const float4*)&Y[base + c0];
    float4 yb = *(const float4*)&Y[base + c1];
    float v[8] = {xa.x + ya.x, xa.y + ya.y, xa.z + ya.z, xa.w + ya.w,
                  xb.x + yb.x, xb.y + yb.y, xb.z + yb.z, xb.w + yb.w};
    float s = 0.f, s2 = 0.f;
#pragma unroll
    for (int i = 0; i < 8; ++i) { s += v[i]; s2 = fmaf(v[i], v[i], s2); }
#pragma unroll
    for (int off = 32; off > 0; off >>= 1) {
        s  += __shfl_xor(s, off);
        s2 += __shfl_xor(s2, off);
    }
    float mean = s * (1.f / D_);
    float var  = s2 * (1.f / D_) - mean * mean;
    float rstd = rsqrtf(var + EPS_);
    float4 ga = *(const float4*)&g[c0];
    float4 gb = *(const float4*)&g[c1];
    float4 ba = *(const float4*)&be[c0];
    float4 bb = *(const float4*)&be[c1];
    float o[8];
    o[0] = (v[0] - mean) * rstd * ga.x + ba.x;
    o[1] = (v[1] - mean) * rstd * ga.y + ba.y;
    o[2] = (v[2] - mean) * rstd * ga.z + ba.z;
    o[3] = (v[3] - mean) * rstd * ga.w + ba.w;
    o[4] = (v[4] - mean) * rstd * gb.x + bb.x;
    o[5] = (v[5] - mean) * rstd * gb.y + bb.y;
    o[6] = (v[6] - mean) * rstd * gb.z + bb.z;
    o[7] = (v[7] - mean) * rstd * gb.w + bb.w;
    *(float4*)&Out[base + c0] = make_float4(o[0], o[1], o[2], o[3]);
    *(float4*)&Out[base + c1] = make_float4(o[4], o[5], o[6], o[7]);
    if (HIOUT) {
        bf16x4 h0, h1;
#pragma unroll
        for (int i = 0; i < 4; ++i) {
            h0[i] = (__bf16)o[i];
            h1[i] = (__bf16)o[4 + i];
        }
        *(bf16x4*)&Oh[base + c0] = h0;
        *(bf16x4*)&Oh[base + c1] = h1;
    }
}

// ---------------- launch ----------------
extern "C" void kernel_launch(void* const* d_in, const int* in_sizes, int n_in,
                              void* d_out, int out_size, void* d_ws, size_t ws_size,
                              hipStream_t stream) {
    const float* embed1 = (const float*)d_in[0];
    const float* embed2 = (const float*)d_in[1];
    const float* cls    = (const float*)d_in[2];
    const float* Wq = (const float*)d_in[3];
    const float* bq = (const float*)d_in[4];
    const float* Wk = (const float*)d_in[5];
    const float* bk = (const float*)d_in[6];
    const float* Wv = (const float*)d_in[7];
    const float* bv = (const float*)d_in[8];
    const float* Wo = (const float*)d_in[9];
    const float* bo = (const float*)d_in[10];
    const float* ln1g = (const float*)d_in[11];
    const float* ln1b = (const float*)d_in[12];
    const float* W1 = (const float*)d_in[13];
    const float* b1 = (const float*)d_in[14];
    const float* W2 = (const float*)d_in[15];
    const float* b2 = (const float*)d_in[16];
    const float* ln2g = (const float*)d_in[17];
    const float* ln2b = (const float*)d_in[18];

    const size_t SZ = (size_t)M_ * D_;        // 4,198,400 floats
    float* ws = (float*)d_ws;
    float* X   = ws;                           // [0,SZ) fp32 residual stream
    __bf16* Xh = (__bf16*)(ws + SZ);           // [SZ,1.5SZ) bf16 of X
    __bf16* X2h = (__bf16*)(ws + SZ + SZ / 2); // [1.5SZ,2SZ) bf16 of X2
    float* Tb  = ws + 2 * SZ;                  // [2SZ,3SZ): fp32 scratch (X2 setup, FFN2 out)
    __bf16* Tbh = (__bf16*)(ws + 2 * SZ + SZ / 2); // merge out (attn phase; Tb fp32 dead then)
    __bf16* Qbh = (__bf16*)(ws + 3 * SZ);      // [3SZ,3.5SZ) bf16 Q (attn phase)
    float* WoOut  = (float*)(ws + 3 * SZ);     // aliases Qbh region (dead after attn)
    __bf16* Kbh = (__bf16*)(ws + 4 * SZ);      // [4SZ,4.5SZ) bf16 K
    __bf16* Vtb = (__bf16*)(ws + 5 * SZ);      // [5SZ,~5.54SZ) bf16 Vt (attn phase)
    __bf16* Hbh = (__bf16*)(ws + 5 * SZ);      // [5SZ,7SZ) bf16 [M,DFF] FFN phase (aliases Vtb)
    float* mlBuf   = ws + 6 * SZ + SZ / 2;     // stats (attn phase) -- past Vt end, dead by FFN
    __bf16* Opart  = (__bf16*)(ws + 7 * SZ);   // [7SZ,8SZ) 2 bf16 partial O (attn phase)
    __bf16* wreg = (__bf16*)(ws + 9 * SZ);     // bf16 weights

    const size_t NQl = (size_t)D_ * D_;                // 262144 per layer
    const size_t NQ  = (size_t)NLAYER_ * NQl;          // 524288
    const size_t NF  = (size_t)NLAYER_ * DFF_ * D_;    // 2097152
    __bf16* Wqh  = wreg;                 // NQ
    __bf16* Wkvh = Wqh + NQ;             // 2*NQ  [NLAYER][1024][512]
    __bf16* Woh  = Wkvh + 2 * NQ;        // NQ
    __bf16* W1h  = Woh + NQ;             // NF
    __bf16* W2h  = W1h + NF;             // NF

    tobf16_kernel<<<(int)(NQ / 4 + 255) / 256, 256, 0, stream>>>(Wq, Wqh, (int)(NQ / 4));
    tobf16_kernel<<<(int)(NQ / 4 + 255) / 256, 256, 0, stream>>>(Wo, Woh, (int)(NQ / 4));
    tobf16_kernel<<<(int)(NF / 4 + 255) / 256, 256, 0, stream>>>(W1, W1h, (int)(NF / 4));
    tobf16_kernel<<<(int)(NF / 4 + 255) / 256, 256, 0, stream>>>(W2, W2h, (int)(NF / 4));
    for (int l = 0; l < NLAYER_; ++l) {
        tobf16_kernel<<<(int)(NQl / 4 + 255) / 256, 256, 0, stream>>>(
            Wk + l * NQl, Wkvh + l * 2 * NQl, (int)(NQl / 4));
        tobf16_kernel<<<(int)(NQl / 4 + 255) / 256, 256, 0, stream>>>(
            Wv + l * NQl, Wkvh + l * 2 * NQl + NQl, (int)(NQl / 4));
    }

    // build X (fp32, persistent) and X2 (fp32 in Tb scratch, converted once)
    float* X2tmp = Tb;
    write_cls_kernel<<<(B_ * D_) / 256, 256, 0, stream>>>(cls, X, X2tmp);
    transpose_embed_kernel<<<dim3(L0_ / 32, D_ / 32, B_), dim3(32, 8), 0, stream>>>(embed1, X);
    transpose_embed_kernel<<<dim3(L0_ / 32, D_ / 32, B_), dim3(32, 8), 0, stream>>>(embed2, X2tmp);
    tobf16_kernel<<<(int)(SZ / 4 + 255) / 256, 256, 0, stream>>>(X, Xh, (int)(SZ / 4));
    tobf16_kernel<<<(int)(SZ / 4 + 255) / 256, 256, 0, stream>>>(X2tmp, X2h, (int)(SZ / 4));

    const int GM = (M_ + 127) / 128;         // 65
    const int g512  = GM * (512 / 64);       // 520
    const int g1024 = GM * (1024 / 64);      // 1040
    const int g2048 = GM * (2048 / 64);      // 2080
    const int gpad  = (B_ * H_ * DH_ * (LP_ - L_) + 255) / 256;
    const int gmerge = (M_ * 64 + 255) / 256;

    for (int l = 0; l < NLAYER_; ++l) {
        const size_t oQ = (size_t)l * NQl;
        const size_t oF = (size_t)l * DFF_ * D_;

        gemm_mfma_kernel<false, 2><<<g512, 256, 0, stream>>>(
            Xh, Wqh + oQ, bq + l * D_, nullptr, Qbh, M_, D_, D_);
        gemm_kv_kernel<<<g1024, 256, 0, stream>>>(
            X2h, Wkvh + l * 2 * NQl, bk + l * D_, bv + l * D_, Kbh, Vtb);
        zero_vt_pad_kernel<<<gpad, 256, 0, stream>>>(Vtb);

        attn_mfma_kernel<<<NSPLIT_ * NQT_ * H_ * B_, 256, 0, stream>>>(
            Qbh, Kbh, Vtb, Opart, mlBuf);
        attn_merge_kernel<<<gmerge, 256, 0, stream>>>(Opart, mlBuf, Tbh);

        gemm_mfma_kernel<false, 0><<<g512, 256, 0, stream>>>(
            Tbh, Woh + oQ, bo + l * D_, WoOut, nullptr, M_, D_, D_);

        add_ln_kernel<true><<<(M_ + 3) / 4, 256, 0, stream>>>(
            X, WoOut, ln1g + l * D_, ln1b + l * D_, X, Xh);

        gemm_mfma_kernel<true, 2><<<g2048, 256, 0, stream>>>(
            Xh, W1h + oF, b1 + l * DFF_, nullptr, Hbh, M_, DFF_, D_);
        gemm_mfma_kernel<false, 0><<<g512, 256, 0, stream>>>(
            Hbh, W2h + oF, b2 + l * D_, Tb, nullptr, M_, D_, DFF_);

        if (l == NLAYER_ - 1) {
            add_ln_kernel<false><<<(M_ + 3) / 4, 256, 0, stream>>>(
                X, Tb, ln2g + l * D_, ln2b + l * D_, (float*)d_out, nullptr);
        } else {
            add_ln_kernel<true><<<(M_ + 3) / 4, 256, 0, stream>>>(
                X, Tb, ln2g + l * D_, ln2b + l * D_, X, Xh);
        }
    }
}